// Round 4
// baseline (2150.599 us; speedup 1.0000x reference)
//
#include <hip/hip_runtime.h>
#include <math.h>

#define D_DIM 128

using bf16x8 = __attribute__((ext_vector_type(8))) short;
using f32x4  = __attribute__((ext_vector_type(4))) float;

__device__ __forceinline__ unsigned short f2bf(float f) {
    unsigned u = __float_as_uint(f);
    u += 0x7fffu + ((u >> 16) & 1u);   // RNE
    return (unsigned short)(u >> 16);
}

// ---------------- type sort (counting sort, T=4, padded to 64) ----------------
__global__ void hist_k(const int* __restrict__ nt, int* __restrict__ cnt, int N) {
    int i = blockIdx.x * 256 + threadIdx.x;
    if (i < N) atomicAdd(&cnt[nt[i]], 1);
}
__global__ void scan_types_k(const int* __restrict__ cnt, int* __restrict__ cursor,
                             int* __restrict__ pad_off) {
    if (threadIdx.x == 0) {
        int s = 0;
        for (int t = 0; t < 4; ++t) {
            pad_off[t] = s;
            cursor[t] = 0;
            s += ((cnt[t] + 63) >> 6) << 6;
        }
        pad_off[4] = s;
    }
}
__global__ void scatter_types_k(const int* __restrict__ nt, int* __restrict__ cursor,
                                const int* __restrict__ pad_off,
                                int* __restrict__ order_p, int N) {
    int i = blockIdx.x * 256 + threadIdx.x;
    if (i < N) {
        int t = nt[i];
        int p = pad_off[t] + atomicAdd(&cursor[t], 1);
        order_p[p] = i;
    }
}

// ---------------- weight convert + transpose to bf16: Wt[t][o][i] ----------------
__global__ void convw_k(const float* __restrict__ Wk, const float* __restrict__ Wq,
                        const float* __restrict__ Wv, const float* __restrict__ Wa,
                        unsigned short* __restrict__ Wkt, unsigned short* __restrict__ Wqt,
                        unsigned short* __restrict__ Wvt, unsigned short* __restrict__ Wat) {
    int i = blockIdx.x * 256 + threadIdx.x;   // 65536 total
    int t = i >> 14, rem = i & 16383, row = rem >> 7, col = rem & 127;
    int d = (t << 14) | (col << 7) | row;
    Wkt[d] = f2bf(Wk[i]);
    Wqt[d] = f2bf(Wq[i]);
    Wvt[d] = f2bf(Wv[i]);
    Wat[d] = f2bf(Wa[i]);
}

// ---------------- dst-CSR build ----------------
__global__ void deg_k(const int* __restrict__ ei, int* __restrict__ deg, int E) {
    int e = blockIdx.x * 256 + threadIdx.x;
    if (e < E) atomicAdd(&deg[ei[E + e]], 1);
}
__global__ void scan1_k(const int* __restrict__ deg, int* __restrict__ excl,
                        int* __restrict__ bsum, int N) {
    __shared__ int s[512];
    int i = blockIdx.x * 512 + threadIdx.x;
    int v = (i < N) ? deg[i] : 0;
    s[threadIdx.x] = v;
    __syncthreads();
    for (int off = 1; off < 512; off <<= 1) {
        int t = (threadIdx.x >= off) ? s[threadIdx.x - off] : 0;
        __syncthreads();
        s[threadIdx.x] += t;
        __syncthreads();
    }
    if (i < N) excl[i] = s[threadIdx.x] - v;
    if (threadIdx.x == 511) bsum[blockIdx.x] = s[511];
}
__global__ void scan2_k(int* __restrict__ bsum, int nb) {
    if (threadIdx.x == 0) {
        int run = 0;
        for (int b = 0; b < nb; ++b) { int t = bsum[b]; bsum[b] = run; run += t; }
    }
}
__global__ void scan3_k(int* __restrict__ excl, const int* __restrict__ bsum, int N) {
    int i = blockIdx.x * 512 + threadIdx.x;
    if (i < N) excl[i] += bsum[blockIdx.x];
}
__global__ void scatter_edges_k(const int* __restrict__ ei, const int* __restrict__ et,
                                const int* __restrict__ off, int* __restrict__ cursor,
                                int* __restrict__ elist, int E) {
    int e = blockIdx.x * 256 + threadIdx.x;
    if (e < E) {
        int dst = ei[E + e];
        int p = off[dst] + atomicAdd(&cursor[dst], 1);
        elist[p] = (ei[e] << 2) | et[e];
    }
}

// ---------------- MFMA K/Q/V projection: 64 type-uniform rows per block ----------------
__global__ __launch_bounds__(256)
void proj_mfma(const float* __restrict__ x, const int* __restrict__ order_p,
               const int* __restrict__ pad_off,
               const unsigned short* __restrict__ Wkt, const float* __restrict__ bk,
               const unsigned short* __restrict__ Wqt, const float* __restrict__ bq,
               const unsigned short* __restrict__ Wvt, const float* __restrict__ bv,
               unsigned short* __restrict__ Kb, float* __restrict__ Qb,
               unsigned short* __restrict__ Vb, int N) {
    __shared__ unsigned xs[64 * 64];   // 64 rows x 128 bf16 (XOR-swizzled), 16 KB
    __shared__ int gid_s[64];
    int tid = threadIdx.x;
    int base = blockIdx.x * 64;
    int t = (base >= pad_off[1]) + (base >= pad_off[2]) + (base >= pad_off[3]);

    if (tid < 64) gid_s[tid] = order_p[base + tid];
    __syncthreads();

    {   // stage x -> bf16 swizzled LDS
        int row = tid >> 2, q = tid & 3;
        int g = gid_s[row];
        const float4* xr = (const float4*)(x + (size_t)(g < 0 ? 0 : g) * 128 + q * 32);
        int swz = (row & 7) << 4;
        #pragma unroll
        for (int v4 = 0; v4 < 8; ++v4) {
            float4 f = (g >= 0) ? xr[v4] : make_float4(0.f, 0.f, 0.f, 0.f);
            unsigned ua = (unsigned)f2bf(f.x) | ((unsigned)f2bf(f.y) << 16);
            unsigned ub = (unsigned)f2bf(f.z) | ((unsigned)f2bf(f.w) << 16);
            int c2 = (q * 16 + v4 * 2) * 4;   // byte offset within row
            xs[(row << 6) + (((c2) ^ swz) >> 2)] = ua;
            xs[(row << 6) + (((c2 + 4) ^ swz) >> 2)] = ub;
        }
    }
    __syncthreads();

    int w = tid >> 6, l = tid & 63;
    int rowbase = w * 16, lr = l & 15, lg = l >> 4;

    bf16x8 afr[4];
    #pragma unroll
    for (int ks = 0; ks < 4; ++ks) {
        int byteoff = (ks * 64 + lg * 16) ^ ((lr & 7) << 4);
        afr[ks] = *reinterpret_cast<const bf16x8*>(
            reinterpret_cast<const char*>(&xs[(rowbase + lr) << 6]) + byteoff);
    }

    int gj[4];
    #pragma unroll
    for (int j = 0; j < 4; ++j) gj[j] = gid_s[rowbase + lg * 4 + j];

    #pragma unroll 1
    for (int c = 0; c < 8; ++c) {
        int col = c * 16 + lr;
        const size_t wbase = ((size_t)t << 14) + (size_t)col * 128 + lg * 8;

        f32x4 ak = {0.f, 0.f, 0.f, 0.f};
        f32x4 aq = {0.f, 0.f, 0.f, 0.f};
        f32x4 av = {0.f, 0.f, 0.f, 0.f};
        #pragma unroll
        for (int ks = 0; ks < 4; ++ks) {
            bf16x8 bk_ = *reinterpret_cast<const bf16x8*>(Wkt + wbase + ks * 32);
            bf16x8 bq_ = *reinterpret_cast<const bf16x8*>(Wqt + wbase + ks * 32);
            bf16x8 bv_ = *reinterpret_cast<const bf16x8*>(Wvt + wbase + ks * 32);
            ak = __builtin_amdgcn_mfma_f32_16x16x32_bf16(afr[ks], bk_, ak, 0, 0, 0);
            aq = __builtin_amdgcn_mfma_f32_16x16x32_bf16(afr[ks], bq_, aq, 0, 0, 0);
            av = __builtin_amdgcn_mfma_f32_16x16x32_bf16(afr[ks], bv_, av, 0, 0, 0);
        }
        float bkv = bk[t * 128 + col], bqv = bq[t * 128 + col], bvv = bv[t * 128 + col];
        #pragma unroll
        for (int j = 0; j < 4; ++j) {
            int g = gj[j];
            if (g >= 0) {
                Kb[(size_t)g * 128 + col] = f2bf(ak[j] + bkv);
                Qb[(size_t)g * 128 + col] = aq[j] + bqv;
                Vb[(size_t)g * 128 + col] = f2bf(av[j] + bvv);
            }
        }
    }
}

// ---------------- fused per-dst edge kernel: one wave per dst, LDS-free ----------------
__global__ __launch_bounds__(256)
void edge_fused(const unsigned short* __restrict__ Kb, const float* __restrict__ Q,
                const unsigned short* __restrict__ Vb,
                const int* __restrict__ off, const int* __restrict__ elist,
                const float* __restrict__ rel_att, const float* __restrict__ rel_msg,
                const float* __restrict__ rel_pri,
                float* __restrict__ aggr, int N, int E) {
    int w = threadIdx.x >> 6, l = threadIdx.x & 63;
    int dst = blockIdx.x * 4 + w;
    if (dst >= N) return;
    int h = l >> 3, j = l & 7;
    int hb = h << 3;
    int d0 = 2 * j;

    float2 qv = *(const float2*)&Q[(size_t)dst * 128 + 2 * l];
    float qk[16];
    #pragma unroll
    for (int kk = 0; kk < 8; ++kk) {
        qk[2 * kk]     = __shfl(qv.x, hb + kk);
        qk[2 * kk + 1] = __shfl(qv.y, hb + kk);
    }

    float qr0[4], qr1[4];
    #pragma unroll
    for (int r = 0; r < 4; ++r) {
        const float* ra = rel_att + ((size_t)(r * 8 + h)) * 256;
        float a0 = 0.f, a1 = 0.f;
        #pragma unroll
        for (int k4 = 0; k4 < 4; ++k4) {
            float4 r0 = *(const float4*)&ra[d0 * 16 + 4 * k4];
            float4 r1 = *(const float4*)&ra[(d0 + 1) * 16 + 4 * k4];
            a0 += qk[4*k4]*r0.x + qk[4*k4+1]*r0.y + qk[4*k4+2]*r0.z + qk[4*k4+3]*r0.w;
            a1 += qk[4*k4]*r1.x + qk[4*k4+1]*r1.y + qk[4*k4+2]*r1.z + qk[4*k4+3]*r1.w;
        }
        float sc = rel_pri[r * 8 + h] * 0.25f;
        qr0[r] = a0 * sc; qr1[r] = a1 * sc;
    }

    float S0[4] = {0.f, 0.f, 0.f, 0.f};
    float S1[4] = {0.f, 0.f, 0.f, 0.f};
    float den = 0.f;

    int e0 = off[dst];
    int e1 = (dst == N - 1) ? E : off[dst + 1];

    for (int base = e0; base < e1; base += 64) {
        int cnt = min(64, e1 - base);
        int pk_l = elist[min(base + l, e1 - 1)];
        for (int s = 0; s < cnt; s += 4) {
            int i1 = min(s + 1, cnt - 1), i2 = min(s + 2, cnt - 1), i3 = min(s + 3, cnt - 1);
            int pk0 = __shfl(pk_l, s);
            int pk1 = __shfl(pk_l, i1);
            int pk2 = __shfl(pk_l, i2);
            int pk3 = __shfl(pk_l, i3);
            unsigned ku0 = *(const unsigned*)&Kb[(size_t)(pk0 >> 2) * 128 + 2 * l];
            unsigned ku1 = *(const unsigned*)&Kb[(size_t)(pk1 >> 2) * 128 + 2 * l];
            unsigned ku2 = *(const unsigned*)&Kb[(size_t)(pk2 >> 2) * 128 + 2 * l];
            unsigned ku3 = *(const unsigned*)&Kb[(size_t)(pk3 >> 2) * 128 + 2 * l];
            unsigned vu0 = *(const unsigned*)&Vb[(size_t)(pk0 >> 2) * 128 + 2 * l];
            unsigned vu1 = *(const unsigned*)&Vb[(size_t)(pk1 >> 2) * 128 + 2 * l];
            unsigned vu2 = *(const unsigned*)&Vb[(size_t)(pk2 >> 2) * 128 + 2 * l];
            unsigned vu3 = *(const unsigned*)&Vb[(size_t)(pk3 >> 2) * 128 + 2 * l];
            int r0 = pk0 & 3, r1 = pk1 & 3, r2 = pk2 & 3, r3 = pk3 & 3;

            float a0 = r0==0?qr0[0]:r0==1?qr0[1]:r0==2?qr0[2]:qr0[3];
            float b0 = r0==0?qr1[0]:r0==1?qr1[1]:r0==2?qr1[2]:qr1[3];
            float a1 = r1==0?qr0[0]:r1==1?qr0[1]:r1==2?qr0[2]:qr0[3];
            float b1 = r1==0?qr1[0]:r1==1?qr1[1]:r1==2?qr1[2]:qr1[3];
            float a2 = r2==0?qr0[0]:r2==1?qr0[1]:r2==2?qr0[2]:qr0[3];
            float b2 = r2==0?qr1[0]:r2==1?qr1[1]:r2==2?qr1[2]:qr1[3];
            float a3 = r3==0?qr0[0]:r3==1?qr0[1]:r3==2?qr0[2]:qr0[3];
            float b3 = r3==0?qr1[0]:r3==1?qr1[1]:r3==2?qr1[2]:qr1[3];

            float k0x = __uint_as_float(ku0 << 16), k0y = __uint_as_float(ku0 & 0xffff0000u);
            float k1x = __uint_as_float(ku1 << 16), k1y = __uint_as_float(ku1 & 0xffff0000u);
            float k2x = __uint_as_float(ku2 << 16), k2y = __uint_as_float(ku2 & 0xffff0000u);
            float k3x = __uint_as_float(ku3 << 16), k3y = __uint_as_float(ku3 & 0xffff0000u);

            float dt0 = k0x * a0 + k0y * b0;
            float dt1 = k1x * a1 + k1y * b1;
            float dt2 = k2x * a2 + k2y * b2;
            float dt3 = k3x * a3 + k3y * b3;
            dt0 += __shfl_xor(dt0, 1); dt1 += __shfl_xor(dt1, 1);
            dt2 += __shfl_xor(dt2, 1); dt3 += __shfl_xor(dt3, 1);
            dt0 += __shfl_xor(dt0, 2); dt1 += __shfl_xor(dt1, 2);
            dt2 += __shfl_xor(dt2, 2); dt3 += __shfl_xor(dt3, 2);
            dt0 += __shfl_xor(dt0, 4); dt1 += __shfl_xor(dt1, 4);
            dt2 += __shfl_xor(dt2, 4); dt3 += __shfl_xor(dt3, 4);

            float w0v = __expf(dt0);
            float w1v = (s + 1 < cnt) ? __expf(dt1) : 0.f;
            float w2v = (s + 2 < cnt) ? __expf(dt2) : 0.f;
            float w3v = (s + 3 < cnt) ? __expf(dt3) : 0.f;
            den += w0v + w1v + w2v + w3v;

            float v0x = __uint_as_float(vu0 << 16), v0y = __uint_as_float(vu0 & 0xffff0000u);
            float v1x = __uint_as_float(vu1 << 16), v1y = __uint_as_float(vu1 & 0xffff0000u);
            float v2x = __uint_as_float(vu2 << 16), v2y = __uint_as_float(vu2 & 0xffff0000u);
            float v3x = __uint_as_float(vu3 << 16), v3y = __uint_as_float(vu3 & 0xffff0000u);

            #pragma unroll
            for (int r = 0; r < 4; ++r) {
                float m0 = (r0 == r) ? w0v : 0.f;
                float m1 = (r1 == r) ? w1v : 0.f;
                float m2 = (r2 == r) ? w2v : 0.f;
                float m3 = (r3 == r) ? w3v : 0.f;
                S0[r] = fmaf(m0, v0x, S0[r]); S1[r] = fmaf(m0, v0y, S1[r]);
                S0[r] = fmaf(m1, v1x, S0[r]); S1[r] = fmaf(m1, v1y, S1[r]);
                S0[r] = fmaf(m2, v2x, S0[r]); S1[r] = fmaf(m2, v2y, S1[r]);
                S0[r] = fmaf(m3, v3x, S0[r]); S1[r] = fmaf(m3, v3y, S1[r]);
            }
        }
    }

    float o0 = 0.f, o1 = 0.f;
    #pragma unroll
    for (int r = 0; r < 4; ++r) {
        const float* rm = rel_msg + ((size_t)(r * 8 + h)) * 256;
        #pragma unroll
        for (int jj = 0; jj < 8; ++jj) {
            float s0 = __shfl(S0[r], hb + jj);
            float s1 = __shfl(S1[r], hb + jj);
            float2 rm0 = *(const float2*)&rm[(2 * jj) * 16 + d0];
            float2 rm1 = *(const float2*)&rm[(2 * jj + 1) * 16 + d0];
            o0 += s0 * rm0.x + s1 * rm1.x;
            o1 += s0 * rm0.y + s1 * rm1.y;
        }
    }
    float inv = (den > 0.f) ? 1.f / den : 0.f;
    *(float2*)&aggr[(size_t)dst * 128 + h * 16 + d0] = make_float2(o0 * inv, o1 * inv);
}

// ---------------- MFMA gelu + Wa proj + skip + LayerNorm ----------------
__global__ __launch_bounds__(256)
void node_out_mfma(const float* __restrict__ aggr, const float* __restrict__ x,
                   const int* __restrict__ order_p, const int* __restrict__ pad_off,
                   const unsigned short* __restrict__ Wat, const float* __restrict__ ba,
                   const float* __restrict__ skip, const float* __restrict__ gamma,
                   const float* __restrict__ beta, float* __restrict__ out, int N) {
    __shared__ unsigned hsm[64 * 64];
    __shared__ int gid_s[64];
    int tid = threadIdx.x;
    int base = blockIdx.x * 64;
    int t = (base >= pad_off[1]) + (base >= pad_off[2]) + (base >= pad_off[3]);

    if (tid < 64) gid_s[tid] = order_p[base + tid];
    __syncthreads();

    {   // stage gelu(aggr) -> bf16 swizzled LDS
        int row = tid >> 2, q = tid & 3;
        int g = gid_s[row];
        const float4* ar = (const float4*)(aggr + (size_t)(g < 0 ? 0 : g) * 128 + q * 32);
        int swz = (row & 7) << 4;
        #pragma unroll
        for (int v4 = 0; v4 < 8; ++v4) {
            float4 f = (g >= 0) ? ar[v4] : make_float4(0.f, 0.f, 0.f, 0.f);
            float g0 = 0.5f * f.x * (1.f + erff(f.x * 0.70710678118654752f));
            float g1 = 0.5f * f.y * (1.f + erff(f.y * 0.70710678118654752f));
            float g2 = 0.5f * f.z * (1.f + erff(f.z * 0.70710678118654752f));
            float g3 = 0.5f * f.w * (1.f + erff(f.w * 0.70710678118654752f));
            unsigned ua = (unsigned)f2bf(g0) | ((unsigned)f2bf(g1) << 16);
            unsigned ub = (unsigned)f2bf(g2) | ((unsigned)f2bf(g3) << 16);
            int c2 = (q * 16 + v4 * 2) * 4;
            hsm[(row << 6) + (((c2) ^ swz) >> 2)] = ua;
            hsm[(row << 6) + (((c2 + 4) ^ swz) >> 2)] = ub;
        }
    }
    __syncthreads();

    int w = tid >> 6, l = tid & 63;
    int rowbase = w * 16, lr = l & 15, lg = l >> 4;

    bf16x8 afr[4];
    #pragma unroll
    for (int ks = 0; ks < 4; ++ks) {
        int byteoff = (ks * 64 + lg * 16) ^ ((lr & 7) << 4);
        afr[ks] = *reinterpret_cast<const bf16x8*>(
            reinterpret_cast<const char*>(&hsm[(rowbase + lr) << 6]) + byteoff);
    }

    float al = 1.f / (1.f + __expf(-skip[t]));
    int gj[4];
    #pragma unroll
    for (int j = 0; j < 4; ++j) gj[j] = gid_s[rowbase + lg * 4 + j];

    float pre[8][4];
    float s[4] = {0.f, 0.f, 0.f, 0.f}, sq[4] = {0.f, 0.f, 0.f, 0.f};

    #pragma unroll 1
    for (int c = 0; c < 8; ++c) {
        int col = c * 16 + lr;
        const unsigned short* wb = Wat + ((size_t)t << 14) + (size_t)col * 128 + lg * 8;
        f32x4 acc = {0.f, 0.f, 0.f, 0.f};
        #pragma unroll
        for (int ks = 0; ks < 4; ++ks) {
            bf16x8 bfr = *reinterpret_cast<const bf16x8*>(wb + ks * 32);
            acc = __builtin_amdgcn_mfma_f32_16x16x32_bf16(afr[ks], bfr, acc, 0, 0, 0);
        }
        float bav = ba[t * 128 + col];
        #pragma unroll
        for (int j = 0; j < 4; ++j) {
            float xv = (gj[j] >= 0) ? x[(size_t)gj[j] * 128 + col] : 0.f;
            float p = (acc[j] + bav) * al + xv * (1.f - al);
            pre[c][j] = p;
            s[j] += p; sq[j] += p * p;
        }
    }

    #pragma unroll
    for (int m = 1; m <= 8; m <<= 1) {
        #pragma unroll
        for (int j = 0; j < 4; ++j) {
            s[j]  += __shfl_xor(s[j], m);
            sq[j] += __shfl_xor(sq[j], m);
        }
    }
    float mu[4], rs[4];
    #pragma unroll
    for (int j = 0; j < 4; ++j) {
        mu[j] = s[j] * (1.f / 128.f);
        float var = sq[j] * (1.f / 128.f) - mu[j] * mu[j];
        rs[j] = rsqrtf(fmaxf(var, 0.f) + 1e-5f);
    }

    #pragma unroll 1
    for (int c = 0; c < 8; ++c) {
        int col = c * 16 + lr;
        float ga = gamma[t * 128 + col], be = beta[t * 128 + col];
        #pragma unroll
        for (int j = 0; j < 4; ++j) {
            if (gj[j] >= 0)
                out[(size_t)gj[j] * 128 + col] = (pre[c][j] - mu[j]) * rs[j] * ga + be;
        }
    }
}

extern "C" void kernel_launch(void* const* d_in, const int* in_sizes, int n_in,
                              void* d_out, int out_size, void* d_ws, size_t ws_size,
                              hipStream_t stream) {
    const float* x   = (const float*)d_in[0];
    const int*   nt  = (const int*)d_in[1];
    const int*   ei  = (const int*)d_in[2];
    const int*   et  = (const int*)d_in[3];
    const float* Wk = (const float*)d_in[5];  const float* bk = (const float*)d_in[6];
    const float* Wq = (const float*)d_in[7];  const float* bq = (const float*)d_in[8];
    const float* Wv = (const float*)d_in[9];  const float* bv = (const float*)d_in[10];
    const float* Wa = (const float*)d_in[11]; const float* ba = (const float*)d_in[12];
    const float* rel_pri = (const float*)d_in[13];
    const float* rel_att = (const float*)d_in[14];
    const float* rel_msg = (const float*)d_in[15];
    const float* skip    = (const float*)d_in[16];
    const float* gamma   = (const float*)d_in[17];
    const float* beta    = (const float*)d_in[18];

    const int N = in_sizes[0] / 128;
    const int E = in_sizes[3];
    const int NB = (N + 511) / 512;

    float* ws = (float*)d_ws;
    float* Qb = ws;                                        // N*128 f32
    float* aggr = Qb + (size_t)N * 128;                    // N*128 f32
    unsigned short* Kb = (unsigned short*)(aggr + (size_t)N * 128);  // N*128 bf16
    unsigned short* Vb = Kb + (size_t)N * 128;             // N*128 bf16
    unsigned short* Wkt = Vb + (size_t)N * 128;            // 65536
    unsigned short* Wqt = Wkt + 65536;
    unsigned short* Wvt = Wqt + 65536;
    unsigned short* Wat = Wvt + 65536;
    int* order_p = (int*)(Wat + 65536);                    // N+320
    int* cnt     = order_p + N + 320;                      // 4
    int* cursorT = cnt + 4;                                // 4
    int* pad_off = cursorT + 4;                            // 8
    int* deg     = pad_off + 8;                            // N
    int* off     = deg + N;                                // N
    int* bsum    = off + N;                                // NB+8
    int* cursorD = bsum + NB + 8;                          // N
    int* elist   = cursorD + N;                            // E

    hipMemsetAsync(cnt, 0, 8 * sizeof(int), stream);
    hipMemsetAsync(order_p, 0xFF, (size_t)(N + 320) * sizeof(int), stream);
    hipMemsetAsync(deg, 0, (size_t)N * sizeof(int), stream);
    hipMemsetAsync(cursorD, 0, (size_t)N * sizeof(int), stream);

    hist_k<<<(N + 255) / 256, 256, 0, stream>>>(nt, cnt, N);
    scan_types_k<<<1, 64, 0, stream>>>(cnt, cursorT, pad_off);
    scatter_types_k<<<(N + 255) / 256, 256, 0, stream>>>(nt, cursorT, pad_off, order_p, N);

    convw_k<<<256, 256, 0, stream>>>(Wk, Wq, Wv, Wa, Wkt, Wqt, Wvt, Wat);

    deg_k<<<(E + 255) / 256, 256, 0, stream>>>(ei, deg, E);
    scan1_k<<<NB, 512, 0, stream>>>(deg, off, bsum, N);
    scan2_k<<<1, 64, 0, stream>>>(bsum, NB);
    scan3_k<<<NB, 512, 0, stream>>>(off, bsum, N);
    scatter_edges_k<<<(E + 255) / 256, 256, 0, stream>>>(ei, et, off, cursorD, elist, E);

    int nb64 = (N + 252 + 63) / 64;
    proj_mfma<<<nb64, 256, 0, stream>>>(x, order_p, pad_off, Wkt, bk, Wqt, bq, Wvt, bv,
                                        Kb, Qb, Vb, N);
    edge_fused<<<(N + 3) / 4, 256, 0, stream>>>(Kb, Qb, Vb, off, elist, rel_att, rel_msg,
                                                rel_pri, aggr, N, E);
    node_out_mfma<<<nb64, 256, 0, stream>>>(aggr, x, order_p, pad_off, Wat, ba, skip,
                                            gamma, beta, (float*)d_out, N);
}

// Round 5
// 892.002 us; speedup vs baseline: 2.4110x; 2.4110x over previous
//
#include <hip/hip_runtime.h>
#include <math.h>

#define D_DIM 128

using bf16x8 = __attribute__((ext_vector_type(8))) short;
using f32x4  = __attribute__((ext_vector_type(4))) float;

__device__ __forceinline__ unsigned short f2bf(float f) {
    unsigned u = __float_as_uint(f);
    u += 0x7fffu + ((u >> 16) & 1u);   // RNE
    return (unsigned short)(u >> 16);
}

// ---------------- type sort: ballot-based stable partition (no global atomics) ----------------
__global__ __launch_bounds__(256)
void count_types_k(const int* __restrict__ nt, int* __restrict__ blockcnt, int N) {
    __shared__ int wcnt[4][4];
    int tid = threadIdx.x;
    int i = blockIdx.x * 256 + tid;
    int w = tid >> 6, l = tid & 63;
    int t = (i < N) ? nt[i] : -1;
    #pragma unroll
    for (int tt = 0; tt < 4; ++tt) {
        unsigned long long m = __ballot(t == tt);
        if (l == 0) wcnt[w][tt] = __popcll(m);
    }
    __syncthreads();
    if (tid < 4) {
        blockcnt[blockIdx.x * 4 + tid] =
            wcnt[0][tid] + wcnt[1][tid] + wcnt[2][tid] + wcnt[3][tid];
    }
}

__global__ __launch_bounds__(256)
void scan_blocks_k(const int* __restrict__ blockcnt, int nb,
                   int* __restrict__ boff, int* __restrict__ pad_off) {
    __shared__ int tot_s[4];
    __shared__ int po_s[5];
    int tid = threadIdx.x;
    int t = tid >> 6, l = tid & 63;
    // pass 1: per-type totals
    int sum = 0;
    for (int base = 0; base < nb; base += 64) {
        int b = base + l;
        sum += (b < nb) ? blockcnt[b * 4 + t] : 0;
    }
    #pragma unroll
    for (int m = 1; m < 64; m <<= 1) sum += __shfl_xor(sum, m);
    if (l == 0) tot_s[t] = sum;
    __syncthreads();
    if (tid == 0) {
        int s = 0;
        for (int tt = 0; tt < 4; ++tt) { po_s[tt] = s; s += ((tot_s[tt] + 63) >> 6) << 6; }
        po_s[4] = s;
        for (int tt = 0; tt < 5; ++tt) pad_off[tt] = po_s[tt];
    }
    __syncthreads();
    // pass 2: exclusive scan per type across blocks (wave t handles type t)
    int run = po_s[t];
    for (int base = 0; base < nb; base += 64) {
        int b = base + l;
        int v = (b < nb) ? blockcnt[b * 4 + t] : 0;
        int incl = v;
        #pragma unroll
        for (int off = 1; off < 64; off <<= 1) {
            int up = __shfl_up(incl, off);
            if (l >= off) incl += up;
        }
        if (b < nb) boff[b * 4 + t] = run + incl - v;
        run += __shfl(incl, 63);
    }
}

__global__ __launch_bounds__(256)
void scatter_types_k(const int* __restrict__ nt, const int* __restrict__ boff,
                     int* __restrict__ order_p, int N) {
    __shared__ int wbase[4][4];
    int tid = threadIdx.x;
    int i = blockIdx.x * 256 + tid;
    int w = tid >> 6, l = tid & 63;
    int t = (i < N) ? nt[i] : -1;
    int rank = 0;
    #pragma unroll
    for (int tt = 0; tt < 4; ++tt) {
        unsigned long long m = __ballot(t == tt);
        if (l == 0) wbase[w][tt] = __popcll(m);
        if (t == tt) rank = __popcll(m & ((1ull << l) - 1ull));
    }
    __syncthreads();
    if (tid < 4) {
        int run = 0;
        for (int ww = 0; ww < 4; ++ww) { int c = wbase[ww][tid]; wbase[ww][tid] = run; run += c; }
    }
    __syncthreads();
    if (i < N) order_p[boff[blockIdx.x * 4 + t] + wbase[w][t] + rank] = i;
}

// ---------------- weight convert + transpose to bf16: Wt[t][o][i] ----------------
__global__ void convw_k(const float* __restrict__ Wk, const float* __restrict__ Wq,
                        const float* __restrict__ Wv, const float* __restrict__ Wa,
                        unsigned short* __restrict__ Wkt, unsigned short* __restrict__ Wqt,
                        unsigned short* __restrict__ Wvt, unsigned short* __restrict__ Wat) {
    int i = blockIdx.x * 256 + threadIdx.x;   // 65536 total
    int t = i >> 14, rem = i & 16383, row = rem >> 7, col = rem & 127;
    int d = (t << 14) | (col << 7) | row;
    Wkt[d] = f2bf(Wk[i]);
    Wqt[d] = f2bf(Wq[i]);
    Wvt[d] = f2bf(Wv[i]);
    Wat[d] = f2bf(Wa[i]);
}

// ---------------- dst-CSR build ----------------
__global__ void deg_k(const int* __restrict__ ei, int* __restrict__ deg, int E) {
    int e = blockIdx.x * 256 + threadIdx.x;
    if (e < E) atomicAdd(&deg[ei[E + e]], 1);
}
__global__ void scan1_k(const int* __restrict__ deg, int* __restrict__ excl,
                        int* __restrict__ bsum, int N) {
    __shared__ int s[512];
    int i = blockIdx.x * 512 + threadIdx.x;
    int v = (i < N) ? deg[i] : 0;
    s[threadIdx.x] = v;
    __syncthreads();
    for (int off = 1; off < 512; off <<= 1) {
        int t = (threadIdx.x >= off) ? s[threadIdx.x - off] : 0;
        __syncthreads();
        s[threadIdx.x] += t;
        __syncthreads();
    }
    if (i < N) excl[i] = s[threadIdx.x] - v;
    if (threadIdx.x == 511) bsum[blockIdx.x] = s[511];
}
__global__ void scan2_k(int* __restrict__ bsum, int nb) {
    // wave-parallel exclusive scan over block sums
    int l = threadIdx.x & 63;
    int run = 0;
    for (int base = 0; base < nb; base += 64) {
        int b = base + l;
        int v = (b < nb) ? bsum[b] : 0;
        int incl = v;
        #pragma unroll
        for (int off = 1; off < 64; off <<= 1) {
            int up = __shfl_up(incl, off);
            if (l >= off) incl += up;
        }
        if (b < nb) bsum[b] = run + incl - v;
        run += __shfl(incl, 63);
    }
}
__global__ void scan3_k(int* __restrict__ excl, const int* __restrict__ bsum, int N) {
    int i = blockIdx.x * 512 + threadIdx.x;
    if (i < N) excl[i] += bsum[blockIdx.x];
}
__global__ void scatter_edges_k(const int* __restrict__ ei, const int* __restrict__ et,
                                const int* __restrict__ off, int* __restrict__ cursor,
                                int* __restrict__ elist, int E) {
    int e = blockIdx.x * 256 + threadIdx.x;
    if (e < E) {
        int dst = ei[E + e];
        int p = off[dst] + atomicAdd(&cursor[dst], 1);
        elist[p] = (ei[e] << 2) | et[e];
    }
}

// ---------------- MFMA K/Q/V projection: 64 type-uniform rows per block ----------------
__global__ __launch_bounds__(256)
void proj_mfma(const float* __restrict__ x, const int* __restrict__ order_p,
               const int* __restrict__ pad_off,
               const unsigned short* __restrict__ Wkt, const float* __restrict__ bk,
               const unsigned short* __restrict__ Wqt, const float* __restrict__ bq,
               const unsigned short* __restrict__ Wvt, const float* __restrict__ bv,
               unsigned short* __restrict__ Kb, float* __restrict__ Qb,
               unsigned short* __restrict__ Vb, int N) {
    __shared__ unsigned xs[64 * 64];   // 64 rows x 128 bf16 (XOR-swizzled), 16 KB
    __shared__ int gid_s[64];
    int tid = threadIdx.x;
    int base = blockIdx.x * 64;
    int t = (base >= pad_off[1]) + (base >= pad_off[2]) + (base >= pad_off[3]);

    if (tid < 64) gid_s[tid] = order_p[base + tid];
    __syncthreads();

    {   // stage x -> bf16 swizzled LDS
        int row = tid >> 2, q = tid & 3;
        int g = gid_s[row];
        const float4* xr = (const float4*)(x + (size_t)(g < 0 ? 0 : g) * 128 + q * 32);
        int swz = (row & 7) << 4;
        #pragma unroll
        for (int v4 = 0; v4 < 8; ++v4) {
            float4 f = (g >= 0) ? xr[v4] : make_float4(0.f, 0.f, 0.f, 0.f);
            unsigned ua = (unsigned)f2bf(f.x) | ((unsigned)f2bf(f.y) << 16);
            unsigned ub = (unsigned)f2bf(f.z) | ((unsigned)f2bf(f.w) << 16);
            int c2 = (q * 16 + v4 * 2) * 4;   // byte offset within row
            xs[(row << 6) + (((c2) ^ swz) >> 2)] = ua;
            xs[(row << 6) + (((c2 + 4) ^ swz) >> 2)] = ub;
        }
    }
    __syncthreads();

    int w = tid >> 6, l = tid & 63;
    int rowbase = w * 16, lr = l & 15, lg = l >> 4;

    bf16x8 afr[4];
    #pragma unroll
    for (int ks = 0; ks < 4; ++ks) {
        int byteoff = (ks * 64 + lg * 16) ^ ((lr & 7) << 4);
        afr[ks] = *reinterpret_cast<const bf16x8*>(
            reinterpret_cast<const char*>(&xs[(rowbase + lr) << 6]) + byteoff);
    }

    int gj[4];
    #pragma unroll
    for (int j = 0; j < 4; ++j) gj[j] = gid_s[rowbase + lg * 4 + j];

    #pragma unroll 1
    for (int c = 0; c < 8; ++c) {
        int col = c * 16 + lr;
        const size_t wbase = ((size_t)t << 14) + (size_t)col * 128 + lg * 8;

        f32x4 ak = {0.f, 0.f, 0.f, 0.f};
        f32x4 aq = {0.f, 0.f, 0.f, 0.f};
        f32x4 av = {0.f, 0.f, 0.f, 0.f};
        #pragma unroll
        for (int ks = 0; ks < 4; ++ks) {
            bf16x8 bk_ = *reinterpret_cast<const bf16x8*>(Wkt + wbase + ks * 32);
            bf16x8 bq_ = *reinterpret_cast<const bf16x8*>(Wqt + wbase + ks * 32);
            bf16x8 bv_ = *reinterpret_cast<const bf16x8*>(Wvt + wbase + ks * 32);
            ak = __builtin_amdgcn_mfma_f32_16x16x32_bf16(afr[ks], bk_, ak, 0, 0, 0);
            aq = __builtin_amdgcn_mfma_f32_16x16x32_bf16(afr[ks], bq_, aq, 0, 0, 0);
            av = __builtin_amdgcn_mfma_f32_16x16x32_bf16(afr[ks], bv_, av, 0, 0, 0);
        }
        float bkv = bk[t * 128 + col], bqv = bq[t * 128 + col], bvv = bv[t * 128 + col];
        #pragma unroll
        for (int j = 0; j < 4; ++j) {
            int g = gj[j];
            if (g >= 0) {
                Kb[(size_t)g * 128 + col] = f2bf(ak[j] + bkv);
                Qb[(size_t)g * 128 + col] = aq[j] + bqv;
                Vb[(size_t)g * 128 + col] = f2bf(av[j] + bvv);
            }
        }
    }
}

// ---------------- fused per-dst edge kernel: one wave per dst, LDS-free ----------------
__global__ __launch_bounds__(256)
void edge_fused(const unsigned short* __restrict__ Kb, const float* __restrict__ Q,
                const unsigned short* __restrict__ Vb,
                const int* __restrict__ off, const int* __restrict__ elist,
                const float* __restrict__ rel_att, const float* __restrict__ rel_msg,
                const float* __restrict__ rel_pri,
                float* __restrict__ aggr, int N, int E) {
    int w = threadIdx.x >> 6, l = threadIdx.x & 63;
    int dst = blockIdx.x * 4 + w;
    if (dst >= N) return;
    int h = l >> 3, j = l & 7;
    int hb = h << 3;
    int d0 = 2 * j;

    float2 qv = *(const float2*)&Q[(size_t)dst * 128 + 2 * l];
    float qk[16];
    #pragma unroll
    for (int kk = 0; kk < 8; ++kk) {
        qk[2 * kk]     = __shfl(qv.x, hb + kk);
        qk[2 * kk + 1] = __shfl(qv.y, hb + kk);
    }

    float qr0[4], qr1[4];
    #pragma unroll
    for (int r = 0; r < 4; ++r) {
        const float* ra = rel_att + ((size_t)(r * 8 + h)) * 256;
        float a0 = 0.f, a1 = 0.f;
        #pragma unroll
        for (int k4 = 0; k4 < 4; ++k4) {
            float4 r0 = *(const float4*)&ra[d0 * 16 + 4 * k4];
            float4 r1 = *(const float4*)&ra[(d0 + 1) * 16 + 4 * k4];
            a0 += qk[4*k4]*r0.x + qk[4*k4+1]*r0.y + qk[4*k4+2]*r0.z + qk[4*k4+3]*r0.w;
            a1 += qk[4*k4]*r1.x + qk[4*k4+1]*r1.y + qk[4*k4+2]*r1.z + qk[4*k4+3]*r1.w;
        }
        float sc = rel_pri[r * 8 + h] * 0.25f;
        qr0[r] = a0 * sc; qr1[r] = a1 * sc;
    }

    float S0[4] = {0.f, 0.f, 0.f, 0.f};
    float S1[4] = {0.f, 0.f, 0.f, 0.f};
    float den = 0.f;

    int e0 = off[dst];
    int e1 = (dst == N - 1) ? E : off[dst + 1];

    for (int base = e0; base < e1; base += 64) {
        int cnt = min(64, e1 - base);
        int pk_l = elist[min(base + l, e1 - 1)];
        for (int s = 0; s < cnt; s += 4) {
            int i1 = min(s + 1, cnt - 1), i2 = min(s + 2, cnt - 1), i3 = min(s + 3, cnt - 1);
            int pk0 = __shfl(pk_l, s);
            int pk1 = __shfl(pk_l, i1);
            int pk2 = __shfl(pk_l, i2);
            int pk3 = __shfl(pk_l, i3);
            unsigned ku0 = *(const unsigned*)&Kb[(size_t)(pk0 >> 2) * 128 + 2 * l];
            unsigned ku1 = *(const unsigned*)&Kb[(size_t)(pk1 >> 2) * 128 + 2 * l];
            unsigned ku2 = *(const unsigned*)&Kb[(size_t)(pk2 >> 2) * 128 + 2 * l];
            unsigned ku3 = *(const unsigned*)&Kb[(size_t)(pk3 >> 2) * 128 + 2 * l];
            unsigned vu0 = *(const unsigned*)&Vb[(size_t)(pk0 >> 2) * 128 + 2 * l];
            unsigned vu1 = *(const unsigned*)&Vb[(size_t)(pk1 >> 2) * 128 + 2 * l];
            unsigned vu2 = *(const unsigned*)&Vb[(size_t)(pk2 >> 2) * 128 + 2 * l];
            unsigned vu3 = *(const unsigned*)&Vb[(size_t)(pk3 >> 2) * 128 + 2 * l];
            int r0 = pk0 & 3, r1 = pk1 & 3, r2 = pk2 & 3, r3 = pk3 & 3;

            float a0 = r0==0?qr0[0]:r0==1?qr0[1]:r0==2?qr0[2]:qr0[3];
            float b0 = r0==0?qr1[0]:r0==1?qr1[1]:r0==2?qr1[2]:qr1[3];
            float a1 = r1==0?qr0[0]:r1==1?qr0[1]:r1==2?qr0[2]:qr0[3];
            float b1 = r1==0?qr1[0]:r1==1?qr1[1]:r1==2?qr1[2]:qr1[3];
            float a2 = r2==0?qr0[0]:r2==1?qr0[1]:r2==2?qr0[2]:qr0[3];
            float b2 = r2==0?qr1[0]:r2==1?qr1[1]:r2==2?qr1[2]:qr1[3];
            float a3 = r3==0?qr0[0]:r3==1?qr0[1]:r3==2?qr0[2]:qr0[3];
            float b3 = r3==0?qr1[0]:r3==1?qr1[1]:r3==2?qr1[2]:qr1[3];

            float k0x = __uint_as_float(ku0 << 16), k0y = __uint_as_float(ku0 & 0xffff0000u);
            float k1x = __uint_as_float(ku1 << 16), k1y = __uint_as_float(ku1 & 0xffff0000u);
            float k2x = __uint_as_float(ku2 << 16), k2y = __uint_as_float(ku2 & 0xffff0000u);
            float k3x = __uint_as_float(ku3 << 16), k3y = __uint_as_float(ku3 & 0xffff0000u);

            float dt0 = k0x * a0 + k0y * b0;
            float dt1 = k1x * a1 + k1y * b1;
            float dt2 = k2x * a2 + k2y * b2;
            float dt3 = k3x * a3 + k3y * b3;
            dt0 += __shfl_xor(dt0, 1); dt1 += __shfl_xor(dt1, 1);
            dt2 += __shfl_xor(dt2, 1); dt3 += __shfl_xor(dt3, 1);
            dt0 += __shfl_xor(dt0, 2); dt1 += __shfl_xor(dt1, 2);
            dt2 += __shfl_xor(dt2, 2); dt3 += __shfl_xor(dt3, 2);
            dt0 += __shfl_xor(dt0, 4); dt1 += __shfl_xor(dt1, 4);
            dt2 += __shfl_xor(dt2, 4); dt3 += __shfl_xor(dt3, 4);

            float w0v = __expf(dt0);
            float w1v = (s + 1 < cnt) ? __expf(dt1) : 0.f;
            float w2v = (s + 2 < cnt) ? __expf(dt2) : 0.f;
            float w3v = (s + 3 < cnt) ? __expf(dt3) : 0.f;
            den += w0v + w1v + w2v + w3v;

            float v0x = __uint_as_float(vu0 << 16), v0y = __uint_as_float(vu0 & 0xffff0000u);
            float v1x = __uint_as_float(vu1 << 16), v1y = __uint_as_float(vu1 & 0xffff0000u);
            float v2x = __uint_as_float(vu2 << 16), v2y = __uint_as_float(vu2 & 0xffff0000u);
            float v3x = __uint_as_float(vu3 << 16), v3y = __uint_as_float(vu3 & 0xffff0000u);

            #pragma unroll
            for (int r = 0; r < 4; ++r) {
                float m0 = (r0 == r) ? w0v : 0.f;
                float m1 = (r1 == r) ? w1v : 0.f;
                float m2 = (r2 == r) ? w2v : 0.f;
                float m3 = (r3 == r) ? w3v : 0.f;
                S0[r] = fmaf(m0, v0x, S0[r]); S1[r] = fmaf(m0, v0y, S1[r]);
                S0[r] = fmaf(m1, v1x, S0[r]); S1[r] = fmaf(m1, v1y, S1[r]);
                S0[r] = fmaf(m2, v2x, S0[r]); S1[r] = fmaf(m2, v2y, S1[r]);
                S0[r] = fmaf(m3, v3x, S0[r]); S1[r] = fmaf(m3, v3y, S1[r]);
            }
        }
    }

    float o0 = 0.f, o1 = 0.f;
    #pragma unroll
    for (int r = 0; r < 4; ++r) {
        const float* rm = rel_msg + ((size_t)(r * 8 + h)) * 256;
        #pragma unroll
        for (int jj = 0; jj < 8; ++jj) {
            float s0 = __shfl(S0[r], hb + jj);
            float s1 = __shfl(S1[r], hb + jj);
            float2 rm0 = *(const float2*)&rm[(2 * jj) * 16 + d0];
            float2 rm1 = *(const float2*)&rm[(2 * jj + 1) * 16 + d0];
            o0 += s0 * rm0.x + s1 * rm1.x;
            o1 += s0 * rm0.y + s1 * rm1.y;
        }
    }
    float inv = (den > 0.f) ? 1.f / den : 0.f;
    *(float2*)&aggr[(size_t)dst * 128 + h * 16 + d0] = make_float2(o0 * inv, o1 * inv);
}

// ---------------- MFMA gelu + Wa proj + skip + LayerNorm ----------------
__global__ __launch_bounds__(256)
void node_out_mfma(const float* __restrict__ aggr, const float* __restrict__ x,
                   const int* __restrict__ order_p, const int* __restrict__ pad_off,
                   const unsigned short* __restrict__ Wat, const float* __restrict__ ba,
                   const float* __restrict__ skip, const float* __restrict__ gamma,
                   const float* __restrict__ beta, float* __restrict__ out, int N) {
    __shared__ unsigned hsm[64 * 64];
    __shared__ int gid_s[64];
    int tid = threadIdx.x;
    int base = blockIdx.x * 64;
    int t = (base >= pad_off[1]) + (base >= pad_off[2]) + (base >= pad_off[3]);

    if (tid < 64) gid_s[tid] = order_p[base + tid];
    __syncthreads();

    {   // stage gelu(aggr) -> bf16 swizzled LDS
        int row = tid >> 2, q = tid & 3;
        int g = gid_s[row];
        const float4* ar = (const float4*)(aggr + (size_t)(g < 0 ? 0 : g) * 128 + q * 32);
        int swz = (row & 7) << 4;
        #pragma unroll
        for (int v4 = 0; v4 < 8; ++v4) {
            float4 f = (g >= 0) ? ar[v4] : make_float4(0.f, 0.f, 0.f, 0.f);
            float g0 = 0.5f * f.x * (1.f + erff(f.x * 0.70710678118654752f));
            float g1 = 0.5f * f.y * (1.f + erff(f.y * 0.70710678118654752f));
            float g2 = 0.5f * f.z * (1.f + erff(f.z * 0.70710678118654752f));
            float g3 = 0.5f * f.w * (1.f + erff(f.w * 0.70710678118654752f));
            unsigned ua = (unsigned)f2bf(g0) | ((unsigned)f2bf(g1) << 16);
            unsigned ub = (unsigned)f2bf(g2) | ((unsigned)f2bf(g3) << 16);
            int c2 = (q * 16 + v4 * 2) * 4;
            hsm[(row << 6) + (((c2) ^ swz) >> 2)] = ua;
            hsm[(row << 6) + (((c2 + 4) ^ swz) >> 2)] = ub;
        }
    }
    __syncthreads();

    int w = tid >> 6, l = tid & 63;
    int rowbase = w * 16, lr = l & 15, lg = l >> 4;

    bf16x8 afr[4];
    #pragma unroll
    for (int ks = 0; ks < 4; ++ks) {
        int byteoff = (ks * 64 + lg * 16) ^ ((lr & 7) << 4);
        afr[ks] = *reinterpret_cast<const bf16x8*>(
            reinterpret_cast<const char*>(&hsm[(rowbase + lr) << 6]) + byteoff);
    }

    float al = 1.f / (1.f + __expf(-skip[t]));
    int gj[4];
    #pragma unroll
    for (int j = 0; j < 4; ++j) gj[j] = gid_s[rowbase + lg * 4 + j];

    float pre[8][4];
    float s[4] = {0.f, 0.f, 0.f, 0.f}, sq[4] = {0.f, 0.f, 0.f, 0.f};

    #pragma unroll 1
    for (int c = 0; c < 8; ++c) {
        int col = c * 16 + lr;
        const unsigned short* wb = Wat + ((size_t)t << 14) + (size_t)col * 128 + lg * 8;
        f32x4 acc = {0.f, 0.f, 0.f, 0.f};
        #pragma unroll
        for (int ks = 0; ks < 4; ++ks) {
            bf16x8 bfr = *reinterpret_cast<const bf16x8*>(wb + ks * 32);
            acc = __builtin_amdgcn_mfma_f32_16x16x32_bf16(afr[ks], bfr, acc, 0, 0, 0);
        }
        float bav = ba[t * 128 + col];
        #pragma unroll
        for (int j = 0; j < 4; ++j) {
            float xv = (gj[j] >= 0) ? x[(size_t)gj[j] * 128 + col] : 0.f;
            float p = (acc[j] + bav) * al + xv * (1.f - al);
            pre[c][j] = p;
            s[j] += p; sq[j] += p * p;
        }
    }

    #pragma unroll
    for (int m = 1; m <= 8; m <<= 1) {
        #pragma unroll
        for (int j = 0; j < 4; ++j) {
            s[j]  += __shfl_xor(s[j], m);
            sq[j] += __shfl_xor(sq[j], m);
        }
    }
    float mu[4], rs[4];
    #pragma unroll
    for (int j = 0; j < 4; ++j) {
        mu[j] = s[j] * (1.f / 128.f);
        float var = sq[j] * (1.f / 128.f) - mu[j] * mu[j];
        rs[j] = rsqrtf(fmaxf(var, 0.f) + 1e-5f);
    }

    #pragma unroll 1
    for (int c = 0; c < 8; ++c) {
        int col = c * 16 + lr;
        float ga = gamma[t * 128 + col], be = beta[t * 128 + col];
        #pragma unroll
        for (int j = 0; j < 4; ++j) {
            if (gj[j] >= 0)
                out[(size_t)gj[j] * 128 + col] = (pre[c][j] - mu[j]) * rs[j] * ga + be;
        }
    }
}

extern "C" void kernel_launch(void* const* d_in, const int* in_sizes, int n_in,
                              void* d_out, int out_size, void* d_ws, size_t ws_size,
                              hipStream_t stream) {
    const float* x   = (const float*)d_in[0];
    const int*   nt  = (const int*)d_in[1];
    const int*   ei  = (const int*)d_in[2];
    const int*   et  = (const int*)d_in[3];
    const float* Wk = (const float*)d_in[5];  const float* bk = (const float*)d_in[6];
    const float* Wq = (const float*)d_in[7];  const float* bq = (const float*)d_in[8];
    const float* Wv = (const float*)d_in[9];  const float* bv = (const float*)d_in[10];
    const float* Wa = (const float*)d_in[11]; const float* ba = (const float*)d_in[12];
    const float* rel_pri = (const float*)d_in[13];
    const float* rel_att = (const float*)d_in[14];
    const float* rel_msg = (const float*)d_in[15];
    const float* skip    = (const float*)d_in[16];
    const float* gamma   = (const float*)d_in[17];
    const float* beta    = (const float*)d_in[18];

    const int N = in_sizes[0] / 128;
    const int E = in_sizes[3];
    const int NB = (N + 511) / 512;       // for CSR scan (512-blocks)
    const int NB256 = (N + 255) / 256;    // for type sort (256-blocks)

    float* ws = (float*)d_ws;
    float* Qb = ws;                                        // N*128 f32
    float* aggr = Qb + (size_t)N * 128;                    // N*128 f32
    unsigned short* Kb = (unsigned short*)(aggr + (size_t)N * 128);  // N*128 bf16
    unsigned short* Vb = Kb + (size_t)N * 128;             // N*128 bf16
    unsigned short* Wkt = Vb + (size_t)N * 128;            // 65536
    unsigned short* Wqt = Wkt + 65536;
    unsigned short* Wvt = Wqt + 65536;
    unsigned short* Wat = Wvt + 65536;
    int* order_p = (int*)(Wat + 65536);                    // N+320
    int* blockcnt = order_p + N + 320;                     // NB256*4
    int* boff     = blockcnt + NB256 * 4;                  // NB256*4
    int* pad_off  = boff + NB256 * 4;                      // 8
    int* deg     = pad_off + 8;                            // N
    int* off     = deg + N;                                // N
    int* bsum    = off + N;                                // NB+8
    int* cursorD = bsum + NB + 8;                          // N
    int* elist   = cursorD + N;                            // E

    hipMemsetAsync(order_p, 0xFF, (size_t)(N + 320) * sizeof(int), stream);
    hipMemsetAsync(deg, 0, (size_t)N * sizeof(int), stream);
    hipMemsetAsync(cursorD, 0, (size_t)N * sizeof(int), stream);

    // type sort: ballot partition, no global atomics
    count_types_k<<<NB256, 256, 0, stream>>>(nt, blockcnt, N);
    scan_blocks_k<<<1, 256, 0, stream>>>(blockcnt, NB256, boff, pad_off);
    scatter_types_k<<<NB256, 256, 0, stream>>>(nt, boff, order_p, N);

    convw_k<<<256, 256, 0, stream>>>(Wk, Wq, Wv, Wa, Wkt, Wqt, Wvt, Wat);

    deg_k<<<(E + 255) / 256, 256, 0, stream>>>(ei, deg, E);
    scan1_k<<<NB, 512, 0, stream>>>(deg, off, bsum, N);
    scan2_k<<<1, 64, 0, stream>>>(bsum, NB);
    scan3_k<<<NB, 512, 0, stream>>>(off, bsum, N);
    scatter_edges_k<<<(E + 255) / 256, 256, 0, stream>>>(ei, et, off, cursorD, elist, E);

    int nb64 = (N + 252 + 63) / 64;
    proj_mfma<<<nb64, 256, 0, stream>>>(x, order_p, pad_off, Wkt, bk, Wqt, bq, Wvt, bv,
                                        Kb, Qb, Vb, N);
    edge_fused<<<(N + 3) / 4, 256, 0, stream>>>(Kb, Qb, Vb, off, elist, rel_att, rel_msg,
                                                rel_pri, aggr, N, E);
    node_out_mfma<<<nb64, 256, 0, stream>>>(aggr, x, order_p, pad_off, Wat, ba, skip,
                                            gamma, beta, (float*)d_out, N);
}

// Round 6
// 804.982 us; speedup vs baseline: 2.6716x; 1.1081x over previous
//
#include <hip/hip_runtime.h>
#include <math.h>

#define D_DIM 128

using bf16x8 = __attribute__((ext_vector_type(8))) short;
using f32x4  = __attribute__((ext_vector_type(4))) float;

__device__ __forceinline__ unsigned short f2bf(float f) {
    unsigned u = __float_as_uint(f);
    u += 0x7fffu + ((u >> 16) & 1u);   // RNE
    return (unsigned short)(u >> 16);
}

// ---------------- type sort: ballot-based stable partition (no global atomics) ----------------
__global__ __launch_bounds__(256)
void count_types_k(const int* __restrict__ nt, int* __restrict__ blockcnt, int N) {
    __shared__ int wcnt[4][4];
    int tid = threadIdx.x;
    int i = blockIdx.x * 256 + tid;
    int w = tid >> 6, l = tid & 63;
    int t = (i < N) ? nt[i] : -1;
    #pragma unroll
    for (int tt = 0; tt < 4; ++tt) {
        unsigned long long m = __ballot(t == tt);
        if (l == 0) wcnt[w][tt] = __popcll(m);
    }
    __syncthreads();
    if (tid < 4) {
        blockcnt[blockIdx.x * 4 + tid] =
            wcnt[0][tid] + wcnt[1][tid] + wcnt[2][tid] + wcnt[3][tid];
    }
}

__global__ __launch_bounds__(256)
void scan_blocks_k(const int* __restrict__ blockcnt, int nb,
                   int* __restrict__ boff, int* __restrict__ pad_off) {
    __shared__ int tot_s[4];
    __shared__ int po_s[5];
    int tid = threadIdx.x;
    int t = tid >> 6, l = tid & 63;
    int sum = 0;
    for (int base = 0; base < nb; base += 64) {
        int b = base + l;
        sum += (b < nb) ? blockcnt[b * 4 + t] : 0;
    }
    #pragma unroll
    for (int m = 1; m < 64; m <<= 1) sum += __shfl_xor(sum, m);
    if (l == 0) tot_s[t] = sum;
    __syncthreads();
    if (tid == 0) {
        int s = 0;
        for (int tt = 0; tt < 4; ++tt) { po_s[tt] = s; s += ((tot_s[tt] + 63) >> 6) << 6; }
        po_s[4] = s;
        for (int tt = 0; tt < 5; ++tt) pad_off[tt] = po_s[tt];
    }
    __syncthreads();
    int run = po_s[t];
    for (int base = 0; base < nb; base += 64) {
        int b = base + l;
        int v = (b < nb) ? blockcnt[b * 4 + t] : 0;
        int incl = v;
        #pragma unroll
        for (int off = 1; off < 64; off <<= 1) {
            int up = __shfl_up(incl, off);
            if (l >= off) incl += up;
        }
        if (b < nb) boff[b * 4 + t] = run + incl - v;
        run += __shfl(incl, 63);
    }
}

__global__ __launch_bounds__(256)
void scatter_types_k(const int* __restrict__ nt, const int* __restrict__ boff,
                     int* __restrict__ order_p, int N) {
    __shared__ int wbase[4][4];
    int tid = threadIdx.x;
    int i = blockIdx.x * 256 + tid;
    int w = tid >> 6, l = tid & 63;
    int t = (i < N) ? nt[i] : -1;
    int rank = 0;
    #pragma unroll
    for (int tt = 0; tt < 4; ++tt) {
        unsigned long long m = __ballot(t == tt);
        if (l == 0) wbase[w][tt] = __popcll(m);
        if (t == tt) rank = __popcll(m & ((1ull << l) - 1ull));
    }
    __syncthreads();
    if (tid < 4) {
        int run = 0;
        for (int ww = 0; ww < 4; ++ww) { int c = wbase[ww][tid]; wbase[ww][tid] = run; run += c; }
    }
    __syncthreads();
    if (i < N) order_p[boff[blockIdx.x * 4 + t] + wbase[w][t] + rank] = i;
}

// ---------------- weight convert + transpose to bf16: Wt[t][o][i] ----------------
__global__ void convw_k(const float* __restrict__ Wk, const float* __restrict__ Wq,
                        const float* __restrict__ Wa,
                        unsigned short* __restrict__ Wkt, unsigned short* __restrict__ Wqt,
                        unsigned short* __restrict__ Wat) {
    int i = blockIdx.x * 256 + threadIdx.x;   // 65536 total
    int t = i >> 14, rem = i & 16383, row = rem >> 7, col = rem & 127;
    int d = (t << 14) | (col << 7) | row;
    Wkt[d] = f2bf(Wk[i]);
    Wqt[d] = f2bf(Wq[i]);
    Wat[d] = f2bf(Wa[i]);
}

// ---------------- combined Wv·rel_msg weights: W_vm_t[(t*4+r)][col][i] bf16 ----------------
__global__ void combine_vm_k(const float* __restrict__ Wv, const float* __restrict__ rel_msg,
                             unsigned short* __restrict__ W_vm_t) {
    int idx = blockIdx.x * 256 + threadIdx.x;  // 262144 = 16*128*128
    int i = idx & 127;
    int col = (idx >> 7) & 127;
    int r = (idx >> 14) & 3;
    int t = idx >> 16;
    int h = col >> 4, k = col & 15;
    const float* wv = Wv + t * 16384 + i * 128 + h * 16;          // [d]
    const float* rm = rel_msg + ((r * 8 + h) * 16) * 16 + k;      // stride 16 over d
    float s = 0.f;
    #pragma unroll
    for (int d = 0; d < 16; ++d) s += wv[d] * rm[d * 16];
    W_vm_t[idx] = f2bf(s);
}
__global__ void combine_bvm_k(const float* __restrict__ bv, const float* __restrict__ rel_msg,
                              float* __restrict__ bvm) {
    int idx = blockIdx.x * 256 + threadIdx.x;  // 2048
    if (idx >= 2048) return;
    int col = idx & 127;
    int r = (idx >> 7) & 3;
    int t = idx >> 9;
    int h = col >> 4, k = col & 15;
    float s = 0.f;
    #pragma unroll
    for (int d = 0; d < 16; ++d)
        s += bv[t * 128 + h * 16 + d] * rel_msg[((r * 8 + h) * 16 + d) * 16 + k];
    bvm[idx] = s;
}

// ---------------- dst-CSR build ----------------
__global__ void deg_k(const int* __restrict__ ei, int* __restrict__ deg, int E) {
    int e = blockIdx.x * 256 + threadIdx.x;
    if (e < E) atomicAdd(&deg[ei[E + e]], 1);
}
__global__ void scan1_k(const int* __restrict__ deg, int* __restrict__ excl,
                        int* __restrict__ bsum, int N) {
    __shared__ int s[512];
    int i = blockIdx.x * 512 + threadIdx.x;
    int v = (i < N) ? deg[i] : 0;
    s[threadIdx.x] = v;
    __syncthreads();
    for (int off = 1; off < 512; off <<= 1) {
        int t = (threadIdx.x >= off) ? s[threadIdx.x - off] : 0;
        __syncthreads();
        s[threadIdx.x] += t;
        __syncthreads();
    }
    if (i < N) excl[i] = s[threadIdx.x] - v;
    if (threadIdx.x == 511) bsum[blockIdx.x] = s[511];
}
__global__ void scan2_k(int* __restrict__ bsum, int nb) {
    int l = threadIdx.x & 63;
    int run = 0;
    for (int base = 0; base < nb; base += 64) {
        int b = base + l;
        int v = (b < nb) ? bsum[b] : 0;
        int incl = v;
        #pragma unroll
        for (int off = 1; off < 64; off <<= 1) {
            int up = __shfl_up(incl, off);
            if (l >= off) incl += up;
        }
        if (b < nb) bsum[b] = run + incl - v;
        run += __shfl(incl, 63);
    }
}
__global__ void scan3_k(int* __restrict__ excl, const int* __restrict__ bsum, int N) {
    int i = blockIdx.x * 512 + threadIdx.x;
    if (i < N) excl[i] += bsum[blockIdx.x];
}
__global__ void scatter_edges_k(const int* __restrict__ ei, const int* __restrict__ et,
                                const int* __restrict__ off, int* __restrict__ cursor,
                                int* __restrict__ elist, int E) {
    int e = blockIdx.x * 256 + threadIdx.x;
    if (e < E) {
        int dst = ei[E + e];
        int p = off[dst] + atomicAdd(&cursor[dst], 1);
        elist[p] = (ei[e] << 2) | et[e];
    }
}

// ---------------- MFMA projection: K, Q, and 4 relation-fused VM rows per node ----------------
__global__ __launch_bounds__(256)
void proj_mfma(const float* __restrict__ x, const int* __restrict__ order_p,
               const int* __restrict__ pad_off,
               const unsigned short* __restrict__ Wkt, const float* __restrict__ bk,
               const unsigned short* __restrict__ Wqt, const float* __restrict__ bq,
               const unsigned short* __restrict__ W_vm_t, const float* __restrict__ bvm,
               unsigned short* __restrict__ Kb, float* __restrict__ Qb,
               unsigned short* __restrict__ VMb, int N) {
    __shared__ unsigned xs[64 * 64];   // 64 rows x 128 bf16 (XOR-swizzled), 16 KB
    __shared__ int gid_s[64];
    int tid = threadIdx.x;
    int base = blockIdx.x * 64;
    int t = (base >= pad_off[1]) + (base >= pad_off[2]) + (base >= pad_off[3]);

    if (tid < 64) gid_s[tid] = order_p[base + tid];
    __syncthreads();

    {   // stage x -> bf16 swizzled LDS
        int row = tid >> 2, q = tid & 3;
        int g = gid_s[row];
        const float4* xr = (const float4*)(x + (size_t)(g < 0 ? 0 : g) * 128 + q * 32);
        int swz = (row & 7) << 4;
        #pragma unroll
        for (int v4 = 0; v4 < 8; ++v4) {
            float4 f = (g >= 0) ? xr[v4] : make_float4(0.f, 0.f, 0.f, 0.f);
            unsigned ua = (unsigned)f2bf(f.x) | ((unsigned)f2bf(f.y) << 16);
            unsigned ub = (unsigned)f2bf(f.z) | ((unsigned)f2bf(f.w) << 16);
            int c2 = (q * 16 + v4 * 2) * 4;
            xs[(row << 6) + (((c2) ^ swz) >> 2)] = ua;
            xs[(row << 6) + (((c2 + 4) ^ swz) >> 2)] = ub;
        }
    }
    __syncthreads();

    int w = tid >> 6, l = tid & 63;
    int rowbase = w * 16, lr = l & 15, lg = l >> 4;

    bf16x8 afr[4];
    #pragma unroll
    for (int ks = 0; ks < 4; ++ks) {
        int byteoff = (ks * 64 + lg * 16) ^ ((lr & 7) << 4);
        afr[ks] = *reinterpret_cast<const bf16x8*>(
            reinterpret_cast<const char*>(&xs[(rowbase + lr) << 6]) + byteoff);
    }

    int gj[4];
    #pragma unroll
    for (int j = 0; j < 4; ++j) gj[j] = gid_s[rowbase + lg * 4 + j];

    #pragma unroll 1
    for (int c = 0; c < 8; ++c) {
        int col = c * 16 + lr;
        const size_t wb = (size_t)col * 128 + lg * 8;
        const unsigned short* pk_ = Wkt + ((size_t)t << 14) + wb;
        const unsigned short* pq_ = Wqt + ((size_t)t << 14) + wb;
        const unsigned short* pv0 = W_vm_t + ((size_t)(t * 4 + 0) << 14) + wb;
        const unsigned short* pv1 = W_vm_t + ((size_t)(t * 4 + 1) << 14) + wb;
        const unsigned short* pv2 = W_vm_t + ((size_t)(t * 4 + 2) << 14) + wb;
        const unsigned short* pv3 = W_vm_t + ((size_t)(t * 4 + 3) << 14) + wb;

        f32x4 ak = {0.f, 0.f, 0.f, 0.f};
        f32x4 aq = {0.f, 0.f, 0.f, 0.f};
        f32x4 av0 = {0.f, 0.f, 0.f, 0.f};
        f32x4 av1 = {0.f, 0.f, 0.f, 0.f};
        f32x4 av2 = {0.f, 0.f, 0.f, 0.f};
        f32x4 av3 = {0.f, 0.f, 0.f, 0.f};
        #pragma unroll
        for (int ks = 0; ks < 4; ++ks) {
            bf16x8 a = afr[ks];
            ak  = __builtin_amdgcn_mfma_f32_16x16x32_bf16(a, *(const bf16x8*)(pk_ + ks * 32), ak, 0, 0, 0);
            aq  = __builtin_amdgcn_mfma_f32_16x16x32_bf16(a, *(const bf16x8*)(pq_ + ks * 32), aq, 0, 0, 0);
            av0 = __builtin_amdgcn_mfma_f32_16x16x32_bf16(a, *(const bf16x8*)(pv0 + ks * 32), av0, 0, 0, 0);
            av1 = __builtin_amdgcn_mfma_f32_16x16x32_bf16(a, *(const bf16x8*)(pv1 + ks * 32), av1, 0, 0, 0);
            av2 = __builtin_amdgcn_mfma_f32_16x16x32_bf16(a, *(const bf16x8*)(pv2 + ks * 32), av2, 0, 0, 0);
            av3 = __builtin_amdgcn_mfma_f32_16x16x32_bf16(a, *(const bf16x8*)(pv3 + ks * 32), av3, 0, 0, 0);
        }
        float bkv = bk[t * 128 + col], bqv = bq[t * 128 + col];
        float bb0 = bvm[(t * 4 + 0) * 128 + col];
        float bb1 = bvm[(t * 4 + 1) * 128 + col];
        float bb2 = bvm[(t * 4 + 2) * 128 + col];
        float bb3 = bvm[(t * 4 + 3) * 128 + col];
        #pragma unroll
        for (int j = 0; j < 4; ++j) {
            int g = gj[j];
            if (g >= 0) {
                Kb[(size_t)g * 128 + col] = f2bf(ak[j] + bkv);
                Qb[(size_t)g * 128 + col] = aq[j] + bqv;
                size_t vb = (size_t)g * 512 + col;
                VMb[vb]       = f2bf(av0[j] + bb0);
                VMb[vb + 128] = f2bf(av1[j] + bb1);
                VMb[vb + 256] = f2bf(av2[j] + bb2);
                VMb[vb + 384] = f2bf(av3[j] + bb3);
            }
        }
    }
}

// ---------------- fused per-dst edge kernel: one wave per dst, LDS-free ----------------
// lane l: head h = l>>3, dims d0 = 2*(l&7), d0+1
__global__ __launch_bounds__(256)
void edge_fused(const unsigned short* __restrict__ Kb, const float* __restrict__ Q,
                const unsigned short* __restrict__ VMb,
                const int* __restrict__ off, const int* __restrict__ elist,
                const float* __restrict__ rel_att, const float* __restrict__ rel_pri,
                float* __restrict__ aggr, int N, int E) {
    int w = threadIdx.x >> 6, l = threadIdx.x & 63;
    int dst = blockIdx.x * 4 + w;
    if (dst >= N) return;
    int h = l >> 3;
    int hb = h << 3;
    int d0 = 2 * (l & 7);

    float2 qv = *(const float2*)&Q[(size_t)dst * 128 + 2 * l];
    float qk[16];
    #pragma unroll
    for (int kk = 0; kk < 8; ++kk) {
        qk[2 * kk]     = __shfl(qv.x, hb + kk);
        qk[2 * kk + 1] = __shfl(qv.y, hb + kk);
    }

    float qr0[4], qr1[4];
    #pragma unroll
    for (int r = 0; r < 4; ++r) {
        const float* ra = rel_att + ((size_t)(r * 8 + h)) * 256;
        float a0 = 0.f, a1 = 0.f;
        #pragma unroll
        for (int k4 = 0; k4 < 4; ++k4) {
            float4 r0 = *(const float4*)&ra[d0 * 16 + 4 * k4];
            float4 r1 = *(const float4*)&ra[(d0 + 1) * 16 + 4 * k4];
            a0 += qk[4*k4]*r0.x + qk[4*k4+1]*r0.y + qk[4*k4+2]*r0.z + qk[4*k4+3]*r0.w;
            a1 += qk[4*k4]*r1.x + qk[4*k4+1]*r1.y + qk[4*k4+2]*r1.z + qk[4*k4+3]*r1.w;
        }
        float sc = rel_pri[r * 8 + h] * 0.25f;
        qr0[r] = a0 * sc; qr1[r] = a1 * sc;
    }

    float S0 = 0.f, S1 = 0.f, den = 0.f;

    int e0 = off[dst];
    int e1 = (dst == N - 1) ? E : off[dst + 1];

    for (int base = e0; base < e1; base += 64) {
        int cnt = min(64, e1 - base);
        int pk_l = elist[min(base + l, e1 - 1)];
        for (int s = 0; s < cnt; s += 4) {
            int i1 = min(s + 1, cnt - 1), i2 = min(s + 2, cnt - 1), i3 = min(s + 3, cnt - 1);
            int pk0 = __shfl(pk_l, s);
            int pk1 = __shfl(pk_l, i1);
            int pk2 = __shfl(pk_l, i2);
            int pk3 = __shfl(pk_l, i3);
            // issue all 8 gathers before any use; VM row index IS pk (src*4+r)
            unsigned ku0 = *(const unsigned*)&Kb[(size_t)(pk0 >> 2) * 128 + 2 * l];
            unsigned ku1 = *(const unsigned*)&Kb[(size_t)(pk1 >> 2) * 128 + 2 * l];
            unsigned ku2 = *(const unsigned*)&Kb[(size_t)(pk2 >> 2) * 128 + 2 * l];
            unsigned ku3 = *(const unsigned*)&Kb[(size_t)(pk3 >> 2) * 128 + 2 * l];
            unsigned vu0 = *(const unsigned*)&VMb[(size_t)pk0 * 128 + 2 * l];
            unsigned vu1 = *(const unsigned*)&VMb[(size_t)pk1 * 128 + 2 * l];
            unsigned vu2 = *(const unsigned*)&VMb[(size_t)pk2 * 128 + 2 * l];
            unsigned vu3 = *(const unsigned*)&VMb[(size_t)pk3 * 128 + 2 * l];
            int r0 = pk0 & 3, r1 = pk1 & 3, r2 = pk2 & 3, r3 = pk3 & 3;

            float a0 = r0==0?qr0[0]:r0==1?qr0[1]:r0==2?qr0[2]:qr0[3];
            float b0 = r0==0?qr1[0]:r0==1?qr1[1]:r0==2?qr1[2]:qr1[3];
            float a1 = r1==0?qr0[0]:r1==1?qr0[1]:r1==2?qr0[2]:qr0[3];
            float b1 = r1==0?qr1[0]:r1==1?qr1[1]:r1==2?qr1[2]:qr1[3];
            float a2 = r2==0?qr0[0]:r2==1?qr0[1]:r2==2?qr0[2]:qr0[3];
            float b2 = r2==0?qr1[0]:r2==1?qr1[1]:r2==2?qr1[2]:qr1[3];
            float a3 = r3==0?qr0[0]:r3==1?qr0[1]:r3==2?qr0[2]:qr0[3];
            float b3 = r3==0?qr1[0]:r3==1?qr1[1]:r3==2?qr1[2]:qr1[3];

            float k0x = __uint_as_float(ku0 << 16), k0y = __uint_as_float(ku0 & 0xffff0000u);
            float k1x = __uint_as_float(ku1 << 16), k1y = __uint_as_float(ku1 & 0xffff0000u);
            float k2x = __uint_as_float(ku2 << 16), k2y = __uint_as_float(ku2 & 0xffff0000u);
            float k3x = __uint_as_float(ku3 << 16), k3y = __uint_as_float(ku3 & 0xffff0000u);

            float dt0 = k0x * a0 + k0y * b0;
            float dt1 = k1x * a1 + k1y * b1;
            float dt2 = k2x * a2 + k2y * b2;
            float dt3 = k3x * a3 + k3y * b3;
            dt0 += __shfl_xor(dt0, 1); dt1 += __shfl_xor(dt1, 1);
            dt2 += __shfl_xor(dt2, 1); dt3 += __shfl_xor(dt3, 1);
            dt0 += __shfl_xor(dt0, 2); dt1 += __shfl_xor(dt1, 2);
            dt2 += __shfl_xor(dt2, 2); dt3 += __shfl_xor(dt3, 2);
            dt0 += __shfl_xor(dt0, 4); dt1 += __shfl_xor(dt1, 4);
            dt2 += __shfl_xor(dt2, 4); dt3 += __shfl_xor(dt3, 4);

            float w0v = __expf(dt0);
            float w1v = (s + 1 < cnt) ? __expf(dt1) : 0.f;
            float w2v = (s + 2 < cnt) ? __expf(dt2) : 0.f;
            float w3v = (s + 3 < cnt) ? __expf(dt3) : 0.f;
            den += w0v + w1v + w2v + w3v;

            float v0x = __uint_as_float(vu0 << 16), v0y = __uint_as_float(vu0 & 0xffff0000u);
            float v1x = __uint_as_float(vu1 << 16), v1y = __uint_as_float(vu1 & 0xffff0000u);
            float v2x = __uint_as_float(vu2 << 16), v2y = __uint_as_float(vu2 & 0xffff0000u);
            float v3x = __uint_as_float(vu3 << 16), v3y = __uint_as_float(vu3 & 0xffff0000u);

            S0 = fmaf(w0v, v0x, S0); S1 = fmaf(w0v, v0y, S1);
            S0 = fmaf(w1v, v1x, S0); S1 = fmaf(w1v, v1y, S1);
            S0 = fmaf(w2v, v2x, S0); S1 = fmaf(w2v, v2y, S1);
            S0 = fmaf(w3v, v3x, S0); S1 = fmaf(w3v, v3y, S1);
        }
    }

    float inv = (den > 0.f) ? 1.f / den : 0.f;
    *(float2*)&aggr[(size_t)dst * 128 + h * 16 + d0] = make_float2(S0 * inv, S1 * inv);
}

// ---------------- MFMA gelu + Wa proj + skip + LayerNorm ----------------
__global__ __launch_bounds__(256)
void node_out_mfma(const float* __restrict__ aggr, const float* __restrict__ x,
                   const int* __restrict__ order_p, const int* __restrict__ pad_off,
                   const unsigned short* __restrict__ Wat, const float* __restrict__ ba,
                   const float* __restrict__ skip, const float* __restrict__ gamma,
                   const float* __restrict__ beta, float* __restrict__ out, int N) {
    __shared__ unsigned hsm[64 * 64];
    __shared__ int gid_s[64];
    int tid = threadIdx.x;
    int base = blockIdx.x * 64;
    int t = (base >= pad_off[1]) + (base >= pad_off[2]) + (base >= pad_off[3]);

    if (tid < 64) gid_s[tid] = order_p[base + tid];
    __syncthreads();

    {   // stage gelu(aggr) -> bf16 swizzled LDS
        int row = tid >> 2, q = tid & 3;
        int g = gid_s[row];
        const float4* ar = (const float4*)(aggr + (size_t)(g < 0 ? 0 : g) * 128 + q * 32);
        int swz = (row & 7) << 4;
        #pragma unroll
        for (int v4 = 0; v4 < 8; ++v4) {
            float4 f = (g >= 0) ? ar[v4] : make_float4(0.f, 0.f, 0.f, 0.f);
            float g0 = 0.5f * f.x * (1.f + erff(f.x * 0.70710678118654752f));
            float g1 = 0.5f * f.y * (1.f + erff(f.y * 0.70710678118654752f));
            float g2 = 0.5f * f.z * (1.f + erff(f.z * 0.70710678118654752f));
            float g3 = 0.5f * f.w * (1.f + erff(f.w * 0.70710678118654752f));
            unsigned ua = (unsigned)f2bf(g0) | ((unsigned)f2bf(g1) << 16);
            unsigned ub = (unsigned)f2bf(g2) | ((unsigned)f2bf(g3) << 16);
            int c2 = (q * 16 + v4 * 2) * 4;
            hsm[(row << 6) + (((c2) ^ swz) >> 2)] = ua;
            hsm[(row << 6) + (((c2 + 4) ^ swz) >> 2)] = ub;
        }
    }
    __syncthreads();

    int w = tid >> 6, l = tid & 63;
    int rowbase = w * 16, lr = l & 15, lg = l >> 4;

    bf16x8 afr[4];
    #pragma unroll
    for (int ks = 0; ks < 4; ++ks) {
        int byteoff = (ks * 64 + lg * 16) ^ ((lr & 7) << 4);
        afr[ks] = *reinterpret_cast<const bf16x8*>(
            reinterpret_cast<const char*>(&hsm[(rowbase + lr) << 6]) + byteoff);
    }

    float al = 1.f / (1.f + __expf(-skip[t]));
    int gj[4];
    #pragma unroll
    for (int j = 0; j < 4; ++j) gj[j] = gid_s[rowbase + lg * 4 + j];

    float pre[8][4];
    float s[4] = {0.f, 0.f, 0.f, 0.f}, sq[4] = {0.f, 0.f, 0.f, 0.f};

    #pragma unroll 1
    for (int c = 0; c < 8; ++c) {
        int col = c * 16 + lr;
        const unsigned short* wb = Wat + ((size_t)t << 14) + (size_t)col * 128 + lg * 8;
        f32x4 acc = {0.f, 0.f, 0.f, 0.f};
        #pragma unroll
        for (int ks = 0; ks < 4; ++ks) {
            bf16x8 bfr = *reinterpret_cast<const bf16x8*>(wb + ks * 32);
            acc = __builtin_amdgcn_mfma_f32_16x16x32_bf16(afr[ks], bfr, acc, 0, 0, 0);
        }
        float bav = ba[t * 128 + col];
        #pragma unroll
        for (int j = 0; j < 4; ++j) {
            float xv = (gj[j] >= 0) ? x[(size_t)gj[j] * 128 + col] : 0.f;
            float p = (acc[j] + bav) * al + xv * (1.f - al);
            pre[c][j] = p;
            s[j] += p; sq[j] += p * p;
        }
    }

    #pragma unroll
    for (int m = 1; m <= 8; m <<= 1) {
        #pragma unroll
        for (int j = 0; j < 4; ++j) {
            s[j]  += __shfl_xor(s[j], m);
            sq[j] += __shfl_xor(sq[j], m);
        }
    }
    float mu[4], rs[4];
    #pragma unroll
    for (int j = 0; j < 4; ++j) {
        mu[j] = s[j] * (1.f / 128.f);
        float var = sq[j] * (1.f / 128.f) - mu[j] * mu[j];
        rs[j] = rsqrtf(fmaxf(var, 0.f) + 1e-5f);
    }

    #pragma unroll 1
    for (int c = 0; c < 8; ++c) {
        int col = c * 16 + lr;
        float ga = gamma[t * 128 + col], be = beta[t * 128 + col];
        #pragma unroll
        for (int j = 0; j < 4; ++j) {
            if (gj[j] >= 0)
                out[(size_t)gj[j] * 128 + col] = (pre[c][j] - mu[j]) * rs[j] * ga + be;
        }
    }
}

extern "C" void kernel_launch(void* const* d_in, const int* in_sizes, int n_in,
                              void* d_out, int out_size, void* d_ws, size_t ws_size,
                              hipStream_t stream) {
    const float* x   = (const float*)d_in[0];
    const int*   nt  = (const int*)d_in[1];
    const int*   ei  = (const int*)d_in[2];
    const int*   et  = (const int*)d_in[3];
    const float* Wk = (const float*)d_in[5];  const float* bk = (const float*)d_in[6];
    const float* Wq = (const float*)d_in[7];  const float* bq = (const float*)d_in[8];
    const float* Wv = (const float*)d_in[9];  const float* bv = (const float*)d_in[10];
    const float* Wa = (const float*)d_in[11]; const float* ba = (const float*)d_in[12];
    const float* rel_pri = (const float*)d_in[13];
    const float* rel_att = (const float*)d_in[14];
    const float* rel_msg = (const float*)d_in[15];
    const float* skip    = (const float*)d_in[16];
    const float* gamma   = (const float*)d_in[17];
    const float* beta    = (const float*)d_in[18];

    const int N = in_sizes[0] / 128;
    const int E = in_sizes[3];
    const int NB = (N + 511) / 512;
    const int NB256 = (N + 255) / 256;

    float* ws = (float*)d_ws;
    float* Qb = ws;                                        // N*128 f32
    float* aggr = Qb + (size_t)N * 128;                    // N*128 f32
    unsigned short* Kb = (unsigned short*)(aggr + (size_t)N * 128);  // N*128 bf16
    unsigned short* VMb = Kb + (size_t)N * 128;            // N*512 bf16
    unsigned short* Wkt = VMb + (size_t)N * 512;           // 65536
    unsigned short* Wqt = Wkt + 65536;
    unsigned short* Wat = Wqt + 65536;
    unsigned short* Wvmt = Wat + 65536;                    // 262144
    float* bvm = (float*)(Wvmt + 262144);                  // 2048
    int* order_p = (int*)(bvm + 2048);                     // N+320
    int* blockcnt = order_p + N + 320;                     // NB256*4
    int* boff     = blockcnt + NB256 * 4;                  // NB256*4
    int* pad_off  = boff + NB256 * 4;                      // 8
    int* deg     = pad_off + 8;                            // N
    int* off     = deg + N;                                // N
    int* bsum    = off + N;                                // NB+8
    int* cursorD = bsum + NB + 8;                          // N
    int* elist   = cursorD + N;                            // E

    hipMemsetAsync(order_p, 0xFF, (size_t)(N + 320) * sizeof(int), stream);
    hipMemsetAsync(deg, 0, (size_t)N * sizeof(int), stream);
    hipMemsetAsync(cursorD, 0, (size_t)N * sizeof(int), stream);

    count_types_k<<<NB256, 256, 0, stream>>>(nt, blockcnt, N);
    scan_blocks_k<<<1, 256, 0, stream>>>(blockcnt, NB256, boff, pad_off);
    scatter_types_k<<<NB256, 256, 0, stream>>>(nt, boff, order_p, N);

    convw_k<<<256, 256, 0, stream>>>(Wk, Wq, Wa, Wkt, Wqt, Wat);
    combine_vm_k<<<1024, 256, 0, stream>>>(Wv, rel_msg, Wvmt);
    combine_bvm_k<<<8, 256, 0, stream>>>(bv, rel_msg, bvm);

    deg_k<<<(E + 255) / 256, 256, 0, stream>>>(ei, deg, E);
    scan1_k<<<NB, 512, 0, stream>>>(deg, off, bsum, N);
    scan2_k<<<1, 64, 0, stream>>>(bsum, NB);
    scan3_k<<<NB, 512, 0, stream>>>(off, bsum, N);
    scatter_edges_k<<<(E + 255) / 256, 256, 0, stream>>>(ei, et, off, cursorD, elist, E);

    int nb64 = (N + 252 + 63) / 64;
    proj_mfma<<<nb64, 256, 0, stream>>>(x, order_p, pad_off, Wkt, bk, Wqt, bq, Wvmt, bvm,
                                        Kb, Qb, VMb, N);
    edge_fused<<<(N + 3) / 4, 256, 0, stream>>>(Kb, Qb, VMb, off, elist, rel_att, rel_pri,
                                                aggr, N, E);
    node_out_mfma<<<nb64, 256, 0, stream>>>(aggr, x, order_p, pad_off, Wat, ba, skip,
                                            gamma, beta, (float*)d_out, N);
}

// Round 7
// 543.238 us; speedup vs baseline: 3.9589x; 1.4818x over previous
//
#include <hip/hip_runtime.h>
#include <math.h>

#define D_DIM 128

using bf16x8 = __attribute__((ext_vector_type(8))) short;
using f32x4  = __attribute__((ext_vector_type(4))) float;

__device__ __forceinline__ unsigned short f2bf(float f) {
    unsigned u = __float_as_uint(f);
    u += 0x7fffu + ((u >> 16) & 1u);   // RNE
    return (unsigned short)(u >> 16);
}

// ---------------- type sort: ballot-based stable partition (no global atomics) ----------------
__global__ __launch_bounds__(256)
void count_types_k(const int* __restrict__ nt, int* __restrict__ blockcnt, int N) {
    __shared__ int wcnt[4][4];
    int tid = threadIdx.x;
    int i = blockIdx.x * 256 + tid;
    int w = tid >> 6, l = tid & 63;
    int t = (i < N) ? nt[i] : -1;
    #pragma unroll
    for (int tt = 0; tt < 4; ++tt) {
        unsigned long long m = __ballot(t == tt);
        if (l == 0) wcnt[w][tt] = __popcll(m);
    }
    __syncthreads();
    if (tid < 4) {
        blockcnt[blockIdx.x * 4 + tid] =
            wcnt[0][tid] + wcnt[1][tid] + wcnt[2][tid] + wcnt[3][tid];
    }
}

__global__ __launch_bounds__(256)
void scan_blocks_k(const int* __restrict__ blockcnt, int nb,
                   int* __restrict__ boff, int* __restrict__ pad_off) {
    __shared__ int tot_s[4];
    __shared__ int po_s[5];
    int tid = threadIdx.x;
    int t = tid >> 6, l = tid & 63;
    int sum = 0;
    for (int base = 0; base < nb; base += 64) {
        int b = base + l;
        sum += (b < nb) ? blockcnt[b * 4 + t] : 0;
    }
    #pragma unroll
    for (int m = 1; m < 64; m <<= 1) sum += __shfl_xor(sum, m);
    if (l == 0) tot_s[t] = sum;
    __syncthreads();
    if (tid == 0) {
        int s = 0;
        for (int tt = 0; tt < 4; ++tt) { po_s[tt] = s; s += ((tot_s[tt] + 63) >> 6) << 6; }
        po_s[4] = s;
        for (int tt = 0; tt < 5; ++tt) pad_off[tt] = po_s[tt];
    }
    __syncthreads();
    int run = po_s[t];
    for (int base = 0; base < nb; base += 64) {
        int b = base + l;
        int v = (b < nb) ? blockcnt[b * 4 + t] : 0;
        int incl = v;
        #pragma unroll
        for (int off = 1; off < 64; off <<= 1) {
            int up = __shfl_up(incl, off);
            if (l >= off) incl += up;
        }
        if (b < nb) boff[b * 4 + t] = run + incl - v;
        run += __shfl(incl, 63);
    }
}

__global__ __launch_bounds__(256)
void scatter_types_k(const int* __restrict__ nt, const int* __restrict__ boff,
                     int* __restrict__ order_p, int N) {
    __shared__ int wbase[4][4];
    int tid = threadIdx.x;
    int i = blockIdx.x * 256 + tid;
    int w = tid >> 6, l = tid & 63;
    int t = (i < N) ? nt[i] : -1;
    int rank = 0;
    #pragma unroll
    for (int tt = 0; tt < 4; ++tt) {
        unsigned long long m = __ballot(t == tt);
        if (l == 0) wbase[w][tt] = __popcll(m);
        if (t == tt) rank = __popcll(m & ((1ull << l) - 1ull));
    }
    __syncthreads();
    if (tid < 4) {
        int run = 0;
        for (int ww = 0; ww < 4; ++ww) { int c = wbase[ww][tid]; wbase[ww][tid] = run; run += c; }
    }
    __syncthreads();
    if (i < N) order_p[boff[blockIdx.x * 4 + t] + wbase[w][t] + rank] = i;
}

// ---------------- weight convert + transpose to bf16: Wt[t][o][i] ----------------
__global__ void convw_k(const float* __restrict__ Wq, const float* __restrict__ Wa,
                        unsigned short* __restrict__ Wqt, unsigned short* __restrict__ Wat) {
    int i = blockIdx.x * 256 + threadIdx.x;   // 65536 total
    int t = i >> 14, rem = i & 16383, row = rem >> 7, col = rem & 127;
    int d = (t << 14) | (col << 7) | row;
    Wqt[d] = f2bf(Wq[i]);
    Wat[d] = f2bf(Wa[i]);
}

// ---------------- combined Wk·rel_att (pri-scaled): W_kr_t[(t*4+r)][col][i] bf16 ----------------
__global__ void combine_kr_k(const float* __restrict__ Wk, const float* __restrict__ rel_att,
                             const float* __restrict__ rel_pri,
                             unsigned short* __restrict__ W_kr_t) {
    int idx = blockIdx.x * 256 + threadIdx.x;  // 262144 = 16*128*128
    int i = idx & 127;
    int col = (idx >> 7) & 127;
    int r = (idx >> 14) & 3;
    int t = idx >> 16;
    int h = col >> 4, k = col & 15;
    const float* wk = Wk + t * 16384 + i * 128 + h * 16;          // over d
    const float* ra = rel_att + ((r * 8 + h) * 16) * 16 + k;      // stride 16 over d
    float s = 0.f;
    #pragma unroll
    for (int d = 0; d < 16; ++d) s += wk[d] * ra[d * 16];
    W_kr_t[idx] = f2bf(s * rel_pri[r * 8 + h] * 0.25f);
}
__global__ void combine_bkr_k(const float* __restrict__ bk, const float* __restrict__ rel_att,
                              const float* __restrict__ rel_pri, float* __restrict__ bkr) {
    int idx = blockIdx.x * 256 + threadIdx.x;  // 2048
    if (idx >= 2048) return;
    int col = idx & 127;
    int r = (idx >> 7) & 3;
    int t = idx >> 9;
    int h = col >> 4, k = col & 15;
    float s = 0.f;
    #pragma unroll
    for (int d = 0; d < 16; ++d)
        s += bk[t * 128 + h * 16 + d] * rel_att[((r * 8 + h) * 16 + d) * 16 + k];
    bkr[idx] = s * rel_pri[r * 8 + h] * 0.25f;
}

// ---------------- combined Wv·rel_msg weights: W_vm_t[(t*4+r)][col][i] bf16 ----------------
__global__ void combine_vm_k(const float* __restrict__ Wv, const float* __restrict__ rel_msg,
                             unsigned short* __restrict__ W_vm_t) {
    int idx = blockIdx.x * 256 + threadIdx.x;  // 262144
    int i = idx & 127;
    int col = (idx >> 7) & 127;
    int r = (idx >> 14) & 3;
    int t = idx >> 16;
    int h = col >> 4, k = col & 15;
    const float* wv = Wv + t * 16384 + i * 128 + h * 16;
    const float* rm = rel_msg + ((r * 8 + h) * 16) * 16 + k;
    float s = 0.f;
    #pragma unroll
    for (int d = 0; d < 16; ++d) s += wv[d] * rm[d * 16];
    W_vm_t[idx] = f2bf(s);
}
__global__ void combine_bvm_k(const float* __restrict__ bv, const float* __restrict__ rel_msg,
                              float* __restrict__ bvm) {
    int idx = blockIdx.x * 256 + threadIdx.x;  // 2048
    if (idx >= 2048) return;
    int col = idx & 127;
    int r = (idx >> 7) & 3;
    int t = idx >> 9;
    int h = col >> 4, k = col & 15;
    float s = 0.f;
    #pragma unroll
    for (int d = 0; d < 16; ++d)
        s += bv[t * 128 + h * 16 + d] * rel_msg[((r * 8 + h) * 16 + d) * 16 + k];
    bvm[idx] = s;
}

// ---------------- dst-CSR build ----------------
__global__ void deg_k(const int* __restrict__ ei, int* __restrict__ deg, int E) {
    int e = blockIdx.x * 256 + threadIdx.x;
    if (e < E) atomicAdd(&deg[ei[E + e]], 1);
}
__global__ void scan1_k(const int* __restrict__ deg, int* __restrict__ excl,
                        int* __restrict__ bsum, int N) {
    __shared__ int s[512];
    int i = blockIdx.x * 512 + threadIdx.x;
    int v = (i < N) ? deg[i] : 0;
    s[threadIdx.x] = v;
    __syncthreads();
    for (int off = 1; off < 512; off <<= 1) {
        int t = (threadIdx.x >= off) ? s[threadIdx.x - off] : 0;
        __syncthreads();
        s[threadIdx.x] += t;
        __syncthreads();
    }
    if (i < N) excl[i] = s[threadIdx.x] - v;
    if (threadIdx.x == 511) bsum[blockIdx.x] = s[511];
}
__global__ void scan2_k(int* __restrict__ bsum, int nb) {
    int l = threadIdx.x & 63;
    int run = 0;
    for (int base = 0; base < nb; base += 64) {
        int b = base + l;
        int v = (b < nb) ? bsum[b] : 0;
        int incl = v;
        #pragma unroll
        for (int off = 1; off < 64; off <<= 1) {
            int up = __shfl_up(incl, off);
            if (l >= off) incl += up;
        }
        if (b < nb) bsum[b] = run + incl - v;
        run += __shfl(incl, 63);
    }
}
__global__ void scan3_k(int* __restrict__ excl, const int* __restrict__ bsum, int N) {
    int i = blockIdx.x * 512 + threadIdx.x;
    if (i < N) excl[i] += bsum[blockIdx.x];
}
__global__ void scatter_edges_k(const int* __restrict__ ei, const int* __restrict__ et,
                                const int* __restrict__ off, int* __restrict__ cursor,
                                int* __restrict__ elist, int E) {
    int e = blockIdx.x * 256 + threadIdx.x;
    if (e < E) {
        int dst = ei[E + e];
        int p = off[dst] + atomicAdd(&cursor[dst], 1);
        elist[p] = (ei[e] << 2) | et[e];
    }
}

// ---------------- MFMA projection: Q + 4 KR + 4 VM rows per node ----------------
__global__ __launch_bounds__(256)
void proj_mfma(const float* __restrict__ x, const int* __restrict__ order_p,
               const int* __restrict__ pad_off,
               const unsigned short* __restrict__ Wqt, const float* __restrict__ bq,
               const unsigned short* __restrict__ W_kr_t, const float* __restrict__ bkr,
               const unsigned short* __restrict__ W_vm_t, const float* __restrict__ bvm,
               unsigned short* __restrict__ Qb, unsigned short* __restrict__ KRb,
               unsigned short* __restrict__ VMb, int N) {
    __shared__ unsigned xs[64 * 64];   // 64 rows x 128 bf16 (XOR-swizzled), 16 KB
    __shared__ int gid_s[64];
    int tid = threadIdx.x;
    int base = blockIdx.x * 64;
    int t = (base >= pad_off[1]) + (base >= pad_off[2]) + (base >= pad_off[3]);

    if (tid < 64) gid_s[tid] = order_p[base + tid];
    __syncthreads();

    {   // stage x -> bf16 swizzled LDS
        int row = tid >> 2, q = tid & 3;
        int g = gid_s[row];
        const float4* xr = (const float4*)(x + (size_t)(g < 0 ? 0 : g) * 128 + q * 32);
        int swz = (row & 7) << 4;
        #pragma unroll
        for (int v4 = 0; v4 < 8; ++v4) {
            float4 f = (g >= 0) ? xr[v4] : make_float4(0.f, 0.f, 0.f, 0.f);
            unsigned ua = (unsigned)f2bf(f.x) | ((unsigned)f2bf(f.y) << 16);
            unsigned ub = (unsigned)f2bf(f.z) | ((unsigned)f2bf(f.w) << 16);
            int c2 = (q * 16 + v4 * 2) * 4;
            xs[(row << 6) + (((c2) ^ swz) >> 2)] = ua;
            xs[(row << 6) + (((c2 + 4) ^ swz) >> 2)] = ub;
        }
    }
    __syncthreads();

    int w = tid >> 6, l = tid & 63;
    int rowbase = w * 16, lr = l & 15, lg = l >> 4;

    bf16x8 afr[4];
    #pragma unroll
    for (int ks = 0; ks < 4; ++ks) {
        int byteoff = (ks * 64 + lg * 16) ^ ((lr & 7) << 4);
        afr[ks] = *reinterpret_cast<const bf16x8*>(
            reinterpret_cast<const char*>(&xs[(rowbase + lr) << 6]) + byteoff);
    }

    int gj[4];
    #pragma unroll
    for (int j = 0; j < 4; ++j) gj[j] = gid_s[rowbase + lg * 4 + j];

    #pragma unroll 1
    for (int c = 0; c < 8; ++c) {
        int col = c * 16 + lr;
        const size_t wb = (size_t)col * 128 + lg * 8;
        const unsigned short* pq_ = Wqt + ((size_t)t << 14) + wb;
        const unsigned short* pk0 = W_kr_t + ((size_t)(t * 4 + 0) << 14) + wb;
        const unsigned short* pk1 = W_kr_t + ((size_t)(t * 4 + 1) << 14) + wb;
        const unsigned short* pk2 = W_kr_t + ((size_t)(t * 4 + 2) << 14) + wb;
        const unsigned short* pk3 = W_kr_t + ((size_t)(t * 4 + 3) << 14) + wb;
        const unsigned short* pv0 = W_vm_t + ((size_t)(t * 4 + 0) << 14) + wb;
        const unsigned short* pv1 = W_vm_t + ((size_t)(t * 4 + 1) << 14) + wb;
        const unsigned short* pv2 = W_vm_t + ((size_t)(t * 4 + 2) << 14) + wb;
        const unsigned short* pv3 = W_vm_t + ((size_t)(t * 4 + 3) << 14) + wb;

        f32x4 aq = {0.f, 0.f, 0.f, 0.f};
        f32x4 ak0 = {0.f, 0.f, 0.f, 0.f}, ak1 = {0.f, 0.f, 0.f, 0.f};
        f32x4 ak2 = {0.f, 0.f, 0.f, 0.f}, ak3 = {0.f, 0.f, 0.f, 0.f};
        f32x4 av0 = {0.f, 0.f, 0.f, 0.f}, av1 = {0.f, 0.f, 0.f, 0.f};
        f32x4 av2 = {0.f, 0.f, 0.f, 0.f}, av3 = {0.f, 0.f, 0.f, 0.f};
        #pragma unroll
        for (int ks = 0; ks < 4; ++ks) {
            bf16x8 a = afr[ks];
            aq  = __builtin_amdgcn_mfma_f32_16x16x32_bf16(a, *(const bf16x8*)(pq_ + ks * 32), aq, 0, 0, 0);
            ak0 = __builtin_amdgcn_mfma_f32_16x16x32_bf16(a, *(const bf16x8*)(pk0 + ks * 32), ak0, 0, 0, 0);
            ak1 = __builtin_amdgcn_mfma_f32_16x16x32_bf16(a, *(const bf16x8*)(pk1 + ks * 32), ak1, 0, 0, 0);
            ak2 = __builtin_amdgcn_mfma_f32_16x16x32_bf16(a, *(const bf16x8*)(pk2 + ks * 32), ak2, 0, 0, 0);
            ak3 = __builtin_amdgcn_mfma_f32_16x16x32_bf16(a, *(const bf16x8*)(pk3 + ks * 32), ak3, 0, 0, 0);
            av0 = __builtin_amdgcn_mfma_f32_16x16x32_bf16(a, *(const bf16x8*)(pv0 + ks * 32), av0, 0, 0, 0);
            av1 = __builtin_amdgcn_mfma_f32_16x16x32_bf16(a, *(const bf16x8*)(pv1 + ks * 32), av1, 0, 0, 0);
            av2 = __builtin_amdgcn_mfma_f32_16x16x32_bf16(a, *(const bf16x8*)(pv2 + ks * 32), av2, 0, 0, 0);
            av3 = __builtin_amdgcn_mfma_f32_16x16x32_bf16(a, *(const bf16x8*)(pv3 + ks * 32), av3, 0, 0, 0);
        }
        float bqv = bq[t * 128 + col];
        float bk0 = bkr[(t * 4 + 0) * 128 + col], bk1 = bkr[(t * 4 + 1) * 128 + col];
        float bk2 = bkr[(t * 4 + 2) * 128 + col], bk3 = bkr[(t * 4 + 3) * 128 + col];
        float bb0 = bvm[(t * 4 + 0) * 128 + col], bb1 = bvm[(t * 4 + 1) * 128 + col];
        float bb2 = bvm[(t * 4 + 2) * 128 + col], bb3 = bvm[(t * 4 + 3) * 128 + col];
        #pragma unroll
        for (int j = 0; j < 4; ++j) {
            int g = gj[j];
            if (g >= 0) {
                Qb[(size_t)g * 128 + col] = f2bf(aq[j] + bqv);
                size_t rb = (size_t)g * 512 + col;
                KRb[rb]       = f2bf(ak0[j] + bk0);
                KRb[rb + 128] = f2bf(ak1[j] + bk1);
                KRb[rb + 256] = f2bf(ak2[j] + bk2);
                KRb[rb + 384] = f2bf(ak3[j] + bk3);
                VMb[rb]       = f2bf(av0[j] + bb0);
                VMb[rb + 128] = f2bf(av1[j] + bb1);
                VMb[rb + 256] = f2bf(av2[j] + bb2);
                VMb[rb + 384] = f2bf(av3[j] + bb3);
            }
        }
    }
}

// ---------------- fused per-dst edge kernel: one wave per dst, 4 edges per round-trip ----------------
// lane l: quarter q=l>>4 (edge within batch), chunk c=l&15 (dims 8c..8c+7, head c>>1)
__global__ __launch_bounds__(256)
void edge_fused(const unsigned short* __restrict__ Qb,
                const unsigned short* __restrict__ KRb,
                const unsigned short* __restrict__ VMb,
                const int* __restrict__ off, const int* __restrict__ elist,
                float* __restrict__ aggr, int N, int E) {
    int w = threadIdx.x >> 6, l = threadIdx.x & 63;
    int dst = blockIdx.x * 4 + w;
    if (dst >= N) return;
    int q = l >> 4, c = l & 15;

    float Qf[8];
    {
        bf16x8 qv = *(const bf16x8*)&Qb[(size_t)dst * 128 + c * 8];
        const unsigned* qu = (const unsigned*)&qv;
        #pragma unroll
        for (int i = 0; i < 4; ++i) {
            Qf[2 * i]     = __uint_as_float(qu[i] << 16);
            Qf[2 * i + 1] = __uint_as_float(qu[i] & 0xffff0000u);
        }
    }

    float S[8] = {0.f, 0.f, 0.f, 0.f, 0.f, 0.f, 0.f, 0.f};
    float den = 0.f;

    int e0 = off[dst];
    int e1 = (dst == N - 1) ? E : off[dst + 1];
    int deg = e1 - e0;

    for (int base = 0; base < deg; base += 64) {
        int cnt = min(64, deg - base);
        int pk_l = elist[e0 + min(base + l, deg - 1)];
        for (int s = 0; s < cnt; s += 8) {
            int eA = min(s + q, cnt - 1);
            int eB = min(s + 4 + q, cnt - 1);
            int pkA = __shfl(pk_l, eA);
            int pkB = __shfl(pk_l, eB);
            // 4 x 16B gathers, issued before any use; 16 lanes cover one 256B row
            bf16x8 krA = *(const bf16x8*)&KRb[(size_t)pkA * 128 + c * 8];
            bf16x8 krB = *(const bf16x8*)&KRb[(size_t)pkB * 128 + c * 8];
            bf16x8 vmA = *(const bf16x8*)&VMb[(size_t)pkA * 128 + c * 8];
            bf16x8 vmB = *(const bf16x8*)&VMb[(size_t)pkB * 128 + c * 8];

            const unsigned* ka = (const unsigned*)&krA;
            const unsigned* kb = (const unsigned*)&krB;
            float dtA = 0.f, dtB = 0.f;
            #pragma unroll
            for (int i = 0; i < 4; ++i) {
                dtA = fmaf(Qf[2*i],   __uint_as_float(ka[i] << 16), dtA);
                dtA = fmaf(Qf[2*i+1], __uint_as_float(ka[i] & 0xffff0000u), dtA);
                dtB = fmaf(Qf[2*i],   __uint_as_float(kb[i] << 16), dtB);
                dtB = fmaf(Qf[2*i+1], __uint_as_float(kb[i] & 0xffff0000u), dtB);
            }
            dtA += __shfl_xor(dtA, 1);   // close the 16-dim head dot (pair lanes)
            dtB += __shfl_xor(dtB, 1);
            float wA = (s + q < cnt) ? __expf(dtA) : 0.f;
            float wB = (s + 4 + q < cnt) ? __expf(dtB) : 0.f;
            den += wA + wB;

            const unsigned* va = (const unsigned*)&vmA;
            const unsigned* vb = (const unsigned*)&vmB;
            #pragma unroll
            for (int i = 0; i < 4; ++i) {
                S[2*i]   = fmaf(wA, __uint_as_float(va[i] << 16), S[2*i]);
                S[2*i+1] = fmaf(wA, __uint_as_float(va[i] & 0xffff0000u), S[2*i+1]);
                S[2*i]   = fmaf(wB, __uint_as_float(vb[i] << 16), S[2*i]);
                S[2*i+1] = fmaf(wB, __uint_as_float(vb[i] & 0xffff0000u), S[2*i+1]);
            }
        }
    }

    // reduce S and den across the 4 quarters
    #pragma unroll
    for (int m = 16; m <= 32; m <<= 1) {
        den += __shfl_xor(den, m);
        #pragma unroll
        for (int i = 0; i < 8; ++i) S[i] += __shfl_xor(S[i], m);
    }
    if (q == 0) {
        float inv = (den > 0.f) ? 1.f / den : 0.f;
        float4 o0 = make_float4(S[0]*inv, S[1]*inv, S[2]*inv, S[3]*inv);
        float4 o1 = make_float4(S[4]*inv, S[5]*inv, S[6]*inv, S[7]*inv);
        *(float4*)&aggr[(size_t)dst * 128 + c * 8]     = o0;
        *(float4*)&aggr[(size_t)dst * 128 + c * 8 + 4] = o1;
    }
}

// ---------------- MFMA gelu + Wa proj + skip + LayerNorm (aggr aliases d_out) ----------------
__global__ __launch_bounds__(256)
void node_out_mfma(const float* __restrict__ aggr, const float* __restrict__ x,
                   const int* __restrict__ order_p, const int* __restrict__ pad_off,
                   const unsigned short* __restrict__ Wat, const float* __restrict__ ba,
                   const float* __restrict__ skip, const float* __restrict__ gamma,
                   const float* __restrict__ beta, float* __restrict__ out, int N) {
    __shared__ unsigned hsm[64 * 64];
    __shared__ int gid_s[64];
    int tid = threadIdx.x;
    int base = blockIdx.x * 64;
    int t = (base >= pad_off[1]) + (base >= pad_off[2]) + (base >= pad_off[3]);

    if (tid < 64) gid_s[tid] = order_p[base + tid];
    __syncthreads();

    {   // stage gelu(aggr) -> bf16 swizzled LDS (reads complete before any out-write below)
        int row = tid >> 2, q = tid & 3;
        int g = gid_s[row];
        const float4* ar = (const float4*)(aggr + (size_t)(g < 0 ? 0 : g) * 128 + q * 32);
        int swz = (row & 7) << 4;
        #pragma unroll
        for (int v4 = 0; v4 < 8; ++v4) {
            float4 f = (g >= 0) ? ar[v4] : make_float4(0.f, 0.f, 0.f, 0.f);
            float g0 = 0.5f * f.x * (1.f + erff(f.x * 0.70710678118654752f));
            float g1 = 0.5f * f.y * (1.f + erff(f.y * 0.70710678118654752f));
            float g2 = 0.5f * f.z * (1.f + erff(f.z * 0.70710678118654752f));
            float g3 = 0.5f * f.w * (1.f + erff(f.w * 0.70710678118654752f));
            unsigned ua = (unsigned)f2bf(g0) | ((unsigned)f2bf(g1) << 16);
            unsigned ub = (unsigned)f2bf(g2) | ((unsigned)f2bf(g3) << 16);
            int c2 = (q * 16 + v4 * 2) * 4;
            hsm[(row << 6) + (((c2) ^ swz) >> 2)] = ua;
            hsm[(row << 6) + (((c2 + 4) ^ swz) >> 2)] = ub;
        }
    }
    __syncthreads();

    int w = tid >> 6, l = tid & 63;
    int rowbase = w * 16, lr = l & 15, lg = l >> 4;

    bf16x8 afr[4];
    #pragma unroll
    for (int ks = 0; ks < 4; ++ks) {
        int byteoff = (ks * 64 + lg * 16) ^ ((lr & 7) << 4);
        afr[ks] = *reinterpret_cast<const bf16x8*>(
            reinterpret_cast<const char*>(&hsm[(rowbase + lr) << 6]) + byteoff);
    }

    float al = 1.f / (1.f + __expf(-skip[t]));
    int gj[4];
    #pragma unroll
    for (int j = 0; j < 4; ++j) gj[j] = gid_s[rowbase + lg * 4 + j];

    float pre[8][4];
    float s[4] = {0.f, 0.f, 0.f, 0.f}, sq[4] = {0.f, 0.f, 0.f, 0.f};

    #pragma unroll 1
    for (int c = 0; c < 8; ++c) {
        int col = c * 16 + lr;
        const unsigned short* wb = Wat + ((size_t)t << 14) + (size_t)col * 128 + lg * 8;
        f32x4 acc = {0.f, 0.f, 0.f, 0.f};
        #pragma unroll
        for (int ks = 0; ks < 4; ++ks) {
            bf16x8 bfr = *reinterpret_cast<const bf16x8*>(wb + ks * 32);
            acc = __builtin_amdgcn_mfma_f32_16x16x32_bf16(afr[ks], bfr, acc, 0, 0, 0);
        }
        float bav = ba[t * 128 + col];
        #pragma unroll
        for (int j = 0; j < 4; ++j) {
            float xv = (gj[j] >= 0) ? x[(size_t)gj[j] * 128 + col] : 0.f;
            float p = (acc[j] + bav) * al + xv * (1.f - al);
            pre[c][j] = p;
            s[j] += p; sq[j] += p * p;
        }
    }

    #pragma unroll
    for (int m = 1; m <= 8; m <<= 1) {
        #pragma unroll
        for (int j = 0; j < 4; ++j) {
            s[j]  += __shfl_xor(s[j], m);
            sq[j] += __shfl_xor(sq[j], m);
        }
    }
    float mu[4], rs[4];
    #pragma unroll
    for (int j = 0; j < 4; ++j) {
        mu[j] = s[j] * (1.f / 128.f);
        float var = sq[j] * (1.f / 128.f) - mu[j] * mu[j];
        rs[j] = rsqrtf(fmaxf(var, 0.f) + 1e-5f);
    }

    #pragma unroll 1
    for (int c = 0; c < 8; ++c) {
        int col = c * 16 + lr;
        float ga = gamma[t * 128 + col], be = beta[t * 128 + col];
        #pragma unroll
        for (int j = 0; j < 4; ++j) {
            if (gj[j] >= 0)
                out[(size_t)gj[j] * 128 + col] = (pre[c][j] - mu[j]) * rs[j] * ga + be;
        }
    }
}

extern "C" void kernel_launch(void* const* d_in, const int* in_sizes, int n_in,
                              void* d_out, int out_size, void* d_ws, size_t ws_size,
                              hipStream_t stream) {
    const float* x   = (const float*)d_in[0];
    const int*   nt  = (const int*)d_in[1];
    const int*   ei  = (const int*)d_in[2];
    const int*   et  = (const int*)d_in[3];
    const float* Wk = (const float*)d_in[5];  const float* bk = (const float*)d_in[6];
    const float* Wq = (const float*)d_in[7];  const float* bq = (const float*)d_in[8];
    const float* Wv = (const float*)d_in[9];  const float* bv = (const float*)d_in[10];
    const float* Wa = (const float*)d_in[11]; const float* ba = (const float*)d_in[12];
    const float* rel_pri = (const float*)d_in[13];
    const float* rel_att = (const float*)d_in[14];
    const float* rel_msg = (const float*)d_in[15];
    const float* skip    = (const float*)d_in[16];
    const float* gamma   = (const float*)d_in[17];
    const float* beta    = (const float*)d_in[18];

    const int N = in_sizes[0] / 128;
    const int E = in_sizes[3];
    const int NB = (N + 511) / 512;
    const int NB256 = (N + 255) / 256;

    unsigned short* Qb  = (unsigned short*)d_ws;           // N*128 bf16
    unsigned short* KRb = Qb + (size_t)N * 128;            // N*512 bf16
    unsigned short* VMb = KRb + (size_t)N * 512;           // N*512 bf16
    unsigned short* Wqt = VMb + (size_t)N * 512;           // 65536
    unsigned short* Wat = Wqt + 65536;                     // 65536
    unsigned short* Wkrt = Wat + 65536;                    // 262144
    unsigned short* Wvmt = Wkrt + 262144;                  // 262144
    float* bkr = (float*)(Wvmt + 262144);                  // 2048
    float* bvm = bkr + 2048;                               // 2048
    int* order_p = (int*)(bvm + 2048);                     // N+320
    int* blockcnt = order_p + N + 320;                     // NB256*4
    int* boff     = blockcnt + NB256 * 4;                  // NB256*4
    int* pad_off  = boff + NB256 * 4;                      // 8
    int* deg     = pad_off + 8;                            // N
    int* off     = deg + N;                                // N
    int* bsum    = off + N;                                // NB+8
    int* cursorD = bsum + NB + 8;                          // N
    int* elist   = cursorD + N;                            // E
    float* aggr  = (float*)d_out;                          // aliases output (safe: see node_out)

    hipMemsetAsync(order_p, 0xFF, (size_t)(N + 320) * sizeof(int), stream);
    hipMemsetAsync(deg, 0, (size_t)N * sizeof(int), stream);
    hipMemsetAsync(cursorD, 0, (size_t)N * sizeof(int), stream);

    count_types_k<<<NB256, 256, 0, stream>>>(nt, blockcnt, N);
    scan_blocks_k<<<1, 256, 0, stream>>>(blockcnt, NB256, boff, pad_off);
    scatter_types_k<<<NB256, 256, 0, stream>>>(nt, boff, order_p, N);

    convw_k<<<256, 256, 0, stream>>>(Wq, Wa, Wqt, Wat);
    combine_kr_k<<<1024, 256, 0, stream>>>(Wk, rel_att, rel_pri, Wkrt);
    combine_bkr_k<<<8, 256, 0, stream>>>(bk, rel_att, rel_pri, bkr);
    combine_vm_k<<<1024, 256, 0, stream>>>(Wv, rel_msg, Wvmt);
    combine_bvm_k<<<8, 256, 0, stream>>>(bv, rel_msg, bvm);

    deg_k<<<(E + 255) / 256, 256, 0, stream>>>(ei, deg, E);
    scan1_k<<<NB, 512, 0, stream>>>(deg, off, bsum, N);
    scan2_k<<<1, 64, 0, stream>>>(bsum, NB);
    scan3_k<<<NB, 512, 0, stream>>>(off, bsum, N);
    scatter_edges_k<<<(E + 255) / 256, 256, 0, stream>>>(ei, et, off, cursorD, elist, E);

    int nb64 = (N + 252 + 63) / 64;
    proj_mfma<<<nb64, 256, 0, stream>>>(x, order_p, pad_off, Wqt, bq, Wkrt, bkr, Wvmt, bvm,
                                        Qb, KRb, VMb, N);
    edge_fused<<<(N + 3) / 4, 256, 0, stream>>>(Qb, KRb, VMb, off, elist, aggr, N, E);
    node_out_mfma<<<nb64, 256, 0, stream>>>(aggr, x, order_p, pad_off, Wat, ba, skip,
                                            gamma, beta, (float*)d_out, N);
}

// Round 8
// 539.896 us; speedup vs baseline: 3.9834x; 1.0062x over previous
//
#include <hip/hip_runtime.h>
#include <math.h>

#define D_DIM 128

using bf16x8 = __attribute__((ext_vector_type(8))) short;
using f32x4  = __attribute__((ext_vector_type(4))) float;

__device__ __forceinline__ unsigned short f2bf(float f) {
    unsigned u = __float_as_uint(f);
    u += 0x7fffu + ((u >> 16) & 1u);   // RNE
    return (unsigned short)(u >> 16);
}

// ---------------- type sort: ballot-based stable partition (no global atomics) ----------------
__global__ __launch_bounds__(256)
void count_types_k(const int* __restrict__ nt, int* __restrict__ blockcnt, int N) {
    __shared__ int wcnt[4][4];
    int tid = threadIdx.x;
    int i = blockIdx.x * 256 + tid;
    int w = tid >> 6, l = tid & 63;
    int t = (i < N) ? nt[i] : -1;
    #pragma unroll
    for (int tt = 0; tt < 4; ++tt) {
        unsigned long long m = __ballot(t == tt);
        if (l == 0) wcnt[w][tt] = __popcll(m);
    }
    __syncthreads();
    if (tid < 4) {
        blockcnt[blockIdx.x * 4 + tid] =
            wcnt[0][tid] + wcnt[1][tid] + wcnt[2][tid] + wcnt[3][tid];
    }
}

__global__ __launch_bounds__(256)
void scan_blocks_k(const int* __restrict__ blockcnt, int nb,
                   int* __restrict__ boff, int* __restrict__ pad_off) {
    __shared__ int tot_s[4];
    __shared__ int po_s[5];
    int tid = threadIdx.x;
    int t = tid >> 6, l = tid & 63;
    int sum = 0;
    for (int base = 0; base < nb; base += 64) {
        int b = base + l;
        sum += (b < nb) ? blockcnt[b * 4 + t] : 0;
    }
    #pragma unroll
    for (int m = 1; m < 64; m <<= 1) sum += __shfl_xor(sum, m);
    if (l == 0) tot_s[t] = sum;
    __syncthreads();
    if (tid == 0) {
        int s = 0;
        for (int tt = 0; tt < 4; ++tt) { po_s[tt] = s; s += ((tot_s[tt] + 63) >> 6) << 6; }
        po_s[4] = s;
        for (int tt = 0; tt < 5; ++tt) pad_off[tt] = po_s[tt];
    }
    __syncthreads();
    int run = po_s[t];
    for (int base = 0; base < nb; base += 64) {
        int b = base + l;
        int v = (b < nb) ? blockcnt[b * 4 + t] : 0;
        int incl = v;
        #pragma unroll
        for (int off = 1; off < 64; off <<= 1) {
            int up = __shfl_up(incl, off);
            if (l >= off) incl += up;
        }
        if (b < nb) boff[b * 4 + t] = run + incl - v;
        run += __shfl(incl, 63);
    }
}

__global__ __launch_bounds__(256)
void scatter_types_k(const int* __restrict__ nt, const int* __restrict__ boff,
                     int* __restrict__ order_p, int N) {
    __shared__ int wbase[4][4];
    int tid = threadIdx.x;
    int i = blockIdx.x * 256 + tid;
    int w = tid >> 6, l = tid & 63;
    int t = (i < N) ? nt[i] : -1;
    int rank = 0;
    #pragma unroll
    for (int tt = 0; tt < 4; ++tt) {
        unsigned long long m = __ballot(t == tt);
        if (l == 0) wbase[w][tt] = __popcll(m);
        if (t == tt) rank = __popcll(m & ((1ull << l) - 1ull));
    }
    __syncthreads();
    if (tid < 4) {
        int run = 0;
        for (int ww = 0; ww < 4; ++ww) { int c = wbase[ww][tid]; wbase[ww][tid] = run; run += c; }
    }
    __syncthreads();
    if (i < N) order_p[boff[blockIdx.x * 4 + t] + wbase[w][t] + rank] = i;
}

// ---------------- weight convert + transpose to bf16: Wt[t][o][i] ----------------
__global__ void convw_k(const float* __restrict__ Wq, const float* __restrict__ Wa,
                        unsigned short* __restrict__ Wqt, unsigned short* __restrict__ Wat) {
    int i = blockIdx.x * 256 + threadIdx.x;   // 65536 total
    int t = i >> 14, rem = i & 16383, row = rem >> 7, col = rem & 127;
    int d = (t << 14) | (col << 7) | row;
    Wqt[d] = f2bf(Wq[i]);
    Wat[d] = f2bf(Wa[i]);
}

// ---------------- combined Wk·rel_att (pri-scaled): W_kr_t[(t*4+r)][col][i] bf16 ----------------
__global__ void combine_kr_k(const float* __restrict__ Wk, const float* __restrict__ rel_att,
                             const float* __restrict__ rel_pri,
                             unsigned short* __restrict__ W_kr_t) {
    int idx = blockIdx.x * 256 + threadIdx.x;  // 262144 = 16*128*128
    int i = idx & 127;
    int col = (idx >> 7) & 127;
    int r = (idx >> 14) & 3;
    int t = idx >> 16;
    int h = col >> 4, k = col & 15;
    const float* wk = Wk + t * 16384 + i * 128 + h * 16;
    const float* ra = rel_att + ((r * 8 + h) * 16) * 16 + k;
    float s = 0.f;
    #pragma unroll
    for (int d = 0; d < 16; ++d) s += wk[d] * ra[d * 16];
    W_kr_t[idx] = f2bf(s * rel_pri[r * 8 + h] * 0.25f);
}
__global__ void combine_bkr_k(const float* __restrict__ bk, const float* __restrict__ rel_att,
                              const float* __restrict__ rel_pri, float* __restrict__ bkr) {
    int idx = blockIdx.x * 256 + threadIdx.x;  // 2048
    if (idx >= 2048) return;
    int col = idx & 127;
    int r = (idx >> 7) & 3;
    int t = idx >> 9;
    int h = col >> 4, k = col & 15;
    float s = 0.f;
    #pragma unroll
    for (int d = 0; d < 16; ++d)
        s += bk[t * 128 + h * 16 + d] * rel_att[((r * 8 + h) * 16 + d) * 16 + k];
    bkr[idx] = s * rel_pri[r * 8 + h] * 0.25f;
}

// ---------------- combined Wv·rel_msg weights: W_vm_t[(t*4+r)][col][i] bf16 ----------------
__global__ void combine_vm_k(const float* __restrict__ Wv, const float* __restrict__ rel_msg,
                             unsigned short* __restrict__ W_vm_t) {
    int idx = blockIdx.x * 256 + threadIdx.x;  // 262144
    int i = idx & 127;
    int col = (idx >> 7) & 127;
    int r = (idx >> 14) & 3;
    int t = idx >> 16;
    int h = col >> 4, k = col & 15;
    const float* wv = Wv + t * 16384 + i * 128 + h * 16;
    const float* rm = rel_msg + ((r * 8 + h) * 16) * 16 + k;
    float s = 0.f;
    #pragma unroll
    for (int d = 0; d < 16; ++d) s += wv[d] * rm[d * 16];
    W_vm_t[idx] = f2bf(s);
}
__global__ void combine_bvm_k(const float* __restrict__ bv, const float* __restrict__ rel_msg,
                              float* __restrict__ bvm) {
    int idx = blockIdx.x * 256 + threadIdx.x;  // 2048
    if (idx >= 2048) return;
    int col = idx & 127;
    int r = (idx >> 7) & 3;
    int t = idx >> 9;
    int h = col >> 4, k = col & 15;
    float s = 0.f;
    #pragma unroll
    for (int d = 0; d < 16; ++d)
        s += bv[t * 128 + h * 16 + d] * rel_msg[((r * 8 + h) * 16 + d) * 16 + k];
    bvm[idx] = s;
}

// ---------------- dst-CSR build ----------------
__global__ void deg_k(const int* __restrict__ ei, int* __restrict__ deg, int E) {
    int e = blockIdx.x * 256 + threadIdx.x;
    if (e < E) atomicAdd(&deg[ei[E + e]], 1);
}
__global__ void scan1_k(const int* __restrict__ deg, int* __restrict__ excl,
                        int* __restrict__ bsum, int N) {
    __shared__ int s[512];
    int i = blockIdx.x * 512 + threadIdx.x;
    int v = (i < N) ? deg[i] : 0;
    s[threadIdx.x] = v;
    __syncthreads();
    for (int off = 1; off < 512; off <<= 1) {
        int t = (threadIdx.x >= off) ? s[threadIdx.x - off] : 0;
        __syncthreads();
        s[threadIdx.x] += t;
        __syncthreads();
    }
    if (i < N) excl[i] = s[threadIdx.x] - v;
    if (threadIdx.x == 511) bsum[blockIdx.x] = s[511];
}
__global__ void scan2_k(int* __restrict__ bsum, int nb) {
    int l = threadIdx.x & 63;
    int run = 0;
    for (int base = 0; base < nb; base += 64) {
        int b = base + l;
        int v = (b < nb) ? bsum[b] : 0;
        int incl = v;
        #pragma unroll
        for (int off = 1; off < 64; off <<= 1) {
            int up = __shfl_up(incl, off);
            if (l >= off) incl += up;
        }
        if (b < nb) bsum[b] = run + incl - v;
        run += __shfl(incl, 63);
    }
}
__global__ void scan3_k(int* __restrict__ excl, const int* __restrict__ bsum, int N) {
    int i = blockIdx.x * 512 + threadIdx.x;
    if (i < N) excl[i] += bsum[blockIdx.x];
}
__global__ void scatter_edges_k(const int* __restrict__ ei, const int* __restrict__ et,
                                const int* __restrict__ off, int* __restrict__ cursor,
                                int* __restrict__ elist, int E) {
    int e = blockIdx.x * 256 + threadIdx.x;
    if (e < E) {
        int dst = ei[E + e];
        int p = off[dst] + atomicAdd(&cursor[dst], 1);
        elist[p] = (ei[e] << 2) | et[e];
    }
}

// ---------------- MFMA projection (transposed D): Q + 4 KR + 4 VM rows per node ----------------
// mfma(Wfrag, xfrag, acc) -> D[outcol][node]: lane holds node=lane&15, outcols c*16+lg*4+reg
__global__ __launch_bounds__(256)
void proj_mfma(const float* __restrict__ x, const int* __restrict__ order_p,
               const int* __restrict__ pad_off,
               const unsigned short* __restrict__ Wqt, const float* __restrict__ bq,
               const unsigned short* __restrict__ W_kr_t, const float* __restrict__ bkr,
               const unsigned short* __restrict__ W_vm_t, const float* __restrict__ bvm,
               unsigned short* __restrict__ Qb, unsigned short* __restrict__ KRb,
               unsigned short* __restrict__ VMb, int N) {
    __shared__ unsigned xs[64 * 64];      // 16 KB x staging (swizzled)
    __shared__ unsigned stage[64 * 128];  // 32 KB output staging (reused per pass)
    __shared__ int gid_s[64];
    char* stageb = (char*)stage;
    int tid = threadIdx.x;
    int base = blockIdx.x * 64;
    int t = (base >= pad_off[1]) + (base >= pad_off[2]) + (base >= pad_off[3]);

    if (tid < 64) gid_s[tid] = order_p[base + tid];
    __syncthreads();

    {   // stage x -> bf16 swizzled LDS
        int row = tid >> 2, q = tid & 3;
        int g = gid_s[row];
        const float4* xr = (const float4*)(x + (size_t)(g < 0 ? 0 : g) * 128 + q * 32);
        int swz = (row & 7) << 4;
        #pragma unroll
        for (int v4 = 0; v4 < 8; ++v4) {
            float4 f = (g >= 0) ? xr[v4] : make_float4(0.f, 0.f, 0.f, 0.f);
            unsigned ua = (unsigned)f2bf(f.x) | ((unsigned)f2bf(f.y) << 16);
            unsigned ub = (unsigned)f2bf(f.z) | ((unsigned)f2bf(f.w) << 16);
            int c2 = (q * 16 + v4 * 2) * 4;
            xs[(row << 6) + (((c2) ^ swz) >> 2)] = ua;
            xs[(row << 6) + (((c2 + 4) ^ swz) >> 2)] = ub;
        }
    }
    __syncthreads();

    int w = tid >> 6, l = tid & 63;
    int rowbase = w * 16, lr = l & 15, lg = l >> 4;
    int myrow = rowbase + lr;       // node slot this lane owns in transposed D

    bf16x8 afr[4];                  // x fragment: node=lr, k-block lg (works as B-operand)
    #pragma unroll
    for (int ks = 0; ks < 4; ++ks) {
        int byteoff = (ks * 64 + lg * 16) ^ ((lr & 7) << 4);
        afr[ks] = *reinterpret_cast<const bf16x8*>(
            reinterpret_cast<const char*>(&xs[myrow << 6]) + byteoff);
    }

    // ---- 4 passes: KR mats (0,1),(2,3); VM mats (0,1),(2,3) ----
    #pragma unroll 1
    for (int pass = 0; pass < 4; ++pass) {
        int m0 = (pass & 1) * 2;
        const unsigned short* Wp;
        const float* bp;
        unsigned short* dstp;
        if (pass < 2) { Wp = W_kr_t; bp = bkr; dstp = KRb; }
        else          { Wp = W_vm_t; bp = bvm; dstp = VMb; }
        Wp += (size_t)(t * 4 + m0) << 14;
        bp += (t * 4 + m0) * 128;

        #pragma unroll 1
        for (int c = 0; c < 8; ++c) {
            #pragma unroll
            for (int mm = 0; mm < 2; ++mm) {
                const unsigned short* wb = Wp + ((size_t)mm << 14)
                                         + (size_t)(c * 16 + lr) * 128 + lg * 8;
                f32x4 acc = {0.f, 0.f, 0.f, 0.f};
                #pragma unroll
                for (int ks = 0; ks < 4; ++ks)
                    acc = __builtin_amdgcn_mfma_f32_16x16x32_bf16(
                        *(const bf16x8*)(wb + ks * 32), afr[ks], acc, 0, 0, 0);
                float4 bb = *(const float4*)&bp[mm * 128 + c * 16 + lg * 4];
                unsigned p0 = (unsigned)f2bf(acc[0] + bb.x) | ((unsigned)f2bf(acc[1] + bb.y) << 16);
                unsigned p1 = (unsigned)f2bf(acc[2] + bb.z) | ((unsigned)f2bf(acc[3] + bb.w) << 16);
                int byte = (myrow * 512 + (mm * 128 + c * 16 + lg * 4) * 2) ^ ((myrow & 7) << 4);
                *(uint2*)(stageb + byte) = make_uint2(p0, p1);
            }
        }
        __syncthreads();
        // coalesced drain: 2 node-rows (512 B each) per wave-instruction
        #pragma unroll
        for (int i = 0; i < 8; ++i) {
            int row = rowbase + i * 2 + (l >> 5);
            int l32 = l & 31;
            int byte = (row * 512 + l32 * 16) ^ ((row & 7) << 4);
            uint4 v = *(const uint4*)(stageb + byte);
            int g = gid_s[row];
            if (g >= 0)
                *(uint4*)&dstp[(size_t)g * 512 + (pass & 1) * 256 + l32 * 8] = v;
        }
        __syncthreads();
    }

    // ---- Q pass (128 outcols, 16 KB staging) ----
    #pragma unroll 1
    for (int c = 0; c < 8; ++c) {
        const unsigned short* wb = Wqt + ((size_t)t << 14) + (size_t)(c * 16 + lr) * 128 + lg * 8;
        f32x4 acc = {0.f, 0.f, 0.f, 0.f};
        #pragma unroll
        for (int ks = 0; ks < 4; ++ks)
            acc = __builtin_amdgcn_mfma_f32_16x16x32_bf16(
                *(const bf16x8*)(wb + ks * 32), afr[ks], acc, 0, 0, 0);
        float4 bb = *(const float4*)&bq[t * 128 + c * 16 + lg * 4];
        unsigned p0 = (unsigned)f2bf(acc[0] + bb.x) | ((unsigned)f2bf(acc[1] + bb.y) << 16);
        unsigned p1 = (unsigned)f2bf(acc[2] + bb.z) | ((unsigned)f2bf(acc[3] + bb.w) << 16);
        int byte = (myrow * 256 + (c * 16 + lg * 4) * 2) ^ ((myrow & 7) << 4);
        *(uint2*)(stageb + byte) = make_uint2(p0, p1);
    }
    __syncthreads();
    #pragma unroll
    for (int i = 0; i < 4; ++i) {
        int row = rowbase + i * 4 + (l >> 4);
        int l16 = l & 15;
        int byte = (row * 256 + l16 * 16) ^ ((row & 7) << 4);
        uint4 v = *(const uint4*)(stageb + byte);
        int g = gid_s[row];
        if (g >= 0) *(uint4*)&Qb[(size_t)g * 128 + l16 * 8] = v;
    }
}

// ---------------- fused per-dst edge kernel: one wave per dst, 4 edges per round-trip ----------------
__global__ __launch_bounds__(256)
void edge_fused(const unsigned short* __restrict__ Qb,
                const unsigned short* __restrict__ KRb,
                const unsigned short* __restrict__ VMb,
                const int* __restrict__ off, const int* __restrict__ elist,
                float* __restrict__ aggr, int N, int E) {
    int w = threadIdx.x >> 6, l = threadIdx.x & 63;
    int dst = blockIdx.x * 4 + w;
    if (dst >= N) return;
    int q = l >> 4, c = l & 15;

    float Qf[8];
    {
        bf16x8 qv = *(const bf16x8*)&Qb[(size_t)dst * 128 + c * 8];
        const unsigned* qu = (const unsigned*)&qv;
        #pragma unroll
        for (int i = 0; i < 4; ++i) {
            Qf[2 * i]     = __uint_as_float(qu[i] << 16);
            Qf[2 * i + 1] = __uint_as_float(qu[i] & 0xffff0000u);
        }
    }

    float S[8] = {0.f, 0.f, 0.f, 0.f, 0.f, 0.f, 0.f, 0.f};
    float den = 0.f;

    int e0 = off[dst];
    int e1 = (dst == N - 1) ? E : off[dst + 1];
    int deg = e1 - e0;

    for (int base = 0; base < deg; base += 64) {
        int cnt = min(64, deg - base);
        int pk_l = elist[e0 + min(base + l, deg - 1)];
        for (int s = 0; s < cnt; s += 8) {
            int eA = min(s + q, cnt - 1);
            int eB = min(s + 4 + q, cnt - 1);
            int pkA = __shfl(pk_l, eA);
            int pkB = __shfl(pk_l, eB);
            bf16x8 krA = *(const bf16x8*)&KRb[(size_t)pkA * 128 + c * 8];
            bf16x8 krB = *(const bf16x8*)&KRb[(size_t)pkB * 128 + c * 8];
            bf16x8 vmA = *(const bf16x8*)&VMb[(size_t)pkA * 128 + c * 8];
            bf16x8 vmB = *(const bf16x8*)&VMb[(size_t)pkB * 128 + c * 8];

            const unsigned* ka = (const unsigned*)&krA;
            const unsigned* kb = (const unsigned*)&krB;
            float dtA = 0.f, dtB = 0.f;
            #pragma unroll
            for (int i = 0; i < 4; ++i) {
                dtA = fmaf(Qf[2*i],   __uint_as_float(ka[i] << 16), dtA);
                dtA = fmaf(Qf[2*i+1], __uint_as_float(ka[i] & 0xffff0000u), dtA);
                dtB = fmaf(Qf[2*i],   __uint_as_float(kb[i] << 16), dtB);
                dtB = fmaf(Qf[2*i+1], __uint_as_float(kb[i] & 0xffff0000u), dtB);
            }
            dtA += __shfl_xor(dtA, 1);
            dtB += __shfl_xor(dtB, 1);
            float wA = (s + q < cnt) ? __expf(dtA) : 0.f;
            float wB = (s + 4 + q < cnt) ? __expf(dtB) : 0.f;
            den += wA + wB;

            const unsigned* va = (const unsigned*)&vmA;
            const unsigned* vb = (const unsigned*)&vmB;
            #pragma unroll
            for (int i = 0; i < 4; ++i) {
                S[2*i]   = fmaf(wA, __uint_as_float(va[i] << 16), S[2*i]);
                S[2*i+1] = fmaf(wA, __uint_as_float(va[i] & 0xffff0000u), S[2*i+1]);
                S[2*i]   = fmaf(wB, __uint_as_float(vb[i] << 16), S[2*i]);
                S[2*i+1] = fmaf(wB, __uint_as_float(vb[i] & 0xffff0000u), S[2*i+1]);
            }
        }
    }

    #pragma unroll
    for (int m = 16; m <= 32; m <<= 1) {
        den += __shfl_xor(den, m);
        #pragma unroll
        for (int i = 0; i < 8; ++i) S[i] += __shfl_xor(S[i], m);
    }
    if (q == 0) {
        float inv = (den > 0.f) ? 1.f / den : 0.f;
        float4 o0 = make_float4(S[0]*inv, S[1]*inv, S[2]*inv, S[3]*inv);
        float4 o1 = make_float4(S[4]*inv, S[5]*inv, S[6]*inv, S[7]*inv);
        *(float4*)&aggr[(size_t)dst * 128 + c * 8]     = o0;
        *(float4*)&aggr[(size_t)dst * 128 + c * 8 + 4] = o1;
    }
}

// ---------------- MFMA gelu + Wa proj + skip + LayerNorm (transposed D, aggr aliases d_out) ----------------
__global__ __launch_bounds__(256)
void node_out_mfma(const float* __restrict__ aggr, const float* __restrict__ x,
                   const int* __restrict__ order_p, const int* __restrict__ pad_off,
                   const unsigned short* __restrict__ Wat, const float* __restrict__ ba,
                   const float* __restrict__ skip, const float* __restrict__ gamma,
                   const float* __restrict__ beta, float* __restrict__ out, int N) {
    __shared__ unsigned hsm[64 * 64];
    __shared__ int gid_s[64];
    int tid = threadIdx.x;
    int base = blockIdx.x * 64;
    int t = (base >= pad_off[1]) + (base >= pad_off[2]) + (base >= pad_off[3]);

    if (tid < 64) gid_s[tid] = order_p[base + tid];
    __syncthreads();

    {   // stage gelu(aggr) -> bf16 swizzled LDS (all reads of d_out complete before writes)
        int row = tid >> 2, q = tid & 3;
        int g = gid_s[row];
        const float4* ar = (const float4*)(aggr + (size_t)(g < 0 ? 0 : g) * 128 + q * 32);
        int swz = (row & 7) << 4;
        #pragma unroll
        for (int v4 = 0; v4 < 8; ++v4) {
            float4 f = (g >= 0) ? ar[v4] : make_float4(0.f, 0.f, 0.f, 0.f);
            float g0 = 0.5f * f.x * (1.f + erff(f.x * 0.70710678118654752f));
            float g1 = 0.5f * f.y * (1.f + erff(f.y * 0.70710678118654752f));
            float g2 = 0.5f * f.z * (1.f + erff(f.z * 0.70710678118654752f));
            float g3 = 0.5f * f.w * (1.f + erff(f.w * 0.70710678118654752f));
            unsigned ua = (unsigned)f2bf(g0) | ((unsigned)f2bf(g1) << 16);
            unsigned ub = (unsigned)f2bf(g2) | ((unsigned)f2bf(g3) << 16);
            int c2 = (q * 16 + v4 * 2) * 4;
            hsm[(row << 6) + (((c2) ^ swz) >> 2)] = ua;
            hsm[(row << 6) + (((c2 + 4) ^ swz) >> 2)] = ub;
        }
    }
    __syncthreads();

    int w = tid >> 6, l = tid & 63;
    int rowbase = w * 16, lr = l & 15, lg = l >> 4;
    int myrow = rowbase + lr;

    bf16x8 afr[4];
    #pragma unroll
    for (int ks = 0; ks < 4; ++ks) {
        int byteoff = (ks * 64 + lg * 16) ^ ((lr & 7) << 4);
        afr[ks] = *reinterpret_cast<const bf16x8*>(
            reinterpret_cast<const char*>(&hsm[myrow << 6]) + byteoff);
    }

    float al = 1.f / (1.f + __expf(-skip[t]));
    int g = gid_s[myrow];

    float pre[8][4];
    float s = 0.f, sq = 0.f;

    #pragma unroll
    for (int c = 0; c < 8; ++c) {
        const unsigned short* wb = Wat + ((size_t)t << 14) + (size_t)(c * 16 + lr) * 128 + lg * 8;
        f32x4 acc = {0.f, 0.f, 0.f, 0.f};
        #pragma unroll
        for (int ks = 0; ks < 4; ++ks)
            acc = __builtin_amdgcn_mfma_f32_16x16x32_bf16(
                *(const bf16x8*)(wb + ks * 32), afr[ks], acc, 0, 0, 0);
        float4 bav = *(const float4*)&ba[t * 128 + c * 16 + lg * 4];
        float4 xv = (g >= 0) ? *(const float4*)&x[(size_t)g * 128 + c * 16 + lg * 4]
                             : make_float4(0.f, 0.f, 0.f, 0.f);
        float p0 = (acc[0] + bav.x) * al + xv.x * (1.f - al);
        float p1 = (acc[1] + bav.y) * al + xv.y * (1.f - al);
        float p2 = (acc[2] + bav.z) * al + xv.z * (1.f - al);
        float p3 = (acc[3] + bav.w) * al + xv.w * (1.f - al);
        pre[c][0] = p0; pre[c][1] = p1; pre[c][2] = p2; pre[c][3] = p3;
        s += p0 + p1 + p2 + p3;
        sq += p0 * p0 + p1 * p1 + p2 * p2 + p3 * p3;
    }

    s  += __shfl_xor(s, 16);  sq += __shfl_xor(sq, 16);
    s  += __shfl_xor(s, 32);  sq += __shfl_xor(sq, 32);
    float mu = s * (1.f / 128.f);
    float var = sq * (1.f / 128.f) - mu * mu;
    float rs = rsqrtf(fmaxf(var, 0.f) + 1e-5f);

    #pragma unroll
    for (int c = 0; c < 8; ++c) {
        float4 ga = *(const float4*)&gamma[t * 128 + c * 16 + lg * 4];
        float4 be = *(const float4*)&beta[t * 128 + c * 16 + lg * 4];
        float4 o;
        o.x = (pre[c][0] - mu) * rs * ga.x + be.x;
        o.y = (pre[c][1] - mu) * rs * ga.y + be.y;
        o.z = (pre[c][2] - mu) * rs * ga.z + be.z;
        o.w = (pre[c][3] - mu) * rs * ga.w + be.w;
        if (g >= 0) *(float4*)&out[(size_t)g * 128 + c * 16 + lg * 4] = o;
    }
}

extern "C" void kernel_launch(void* const* d_in, const int* in_sizes, int n_in,
                              void* d_out, int out_size, void* d_ws, size_t ws_size,
                              hipStream_t stream) {
    const float* x   = (const float*)d_in[0];
    const int*   nt  = (const int*)d_in[1];
    const int*   ei  = (const int*)d_in[2];
    const int*   et  = (const int*)d_in[3];
    const float* Wk = (const float*)d_in[5];  const float* bk = (const float*)d_in[6];
    const float* Wq = (const float*)d_in[7];  const float* bq = (const float*)d_in[8];
    const float* Wv = (const float*)d_in[9];  const float* bv = (const float*)d_in[10];
    const float* Wa = (const float*)d_in[11]; const float* ba = (const float*)d_in[12];
    const float* rel_pri = (const float*)d_in[13];
    const float* rel_att = (const float*)d_in[14];
    const float* rel_msg = (const float*)d_in[15];
    const float* skip    = (const float*)d_in[16];
    const float* gamma   = (const float*)d_in[17];
    const float* beta    = (const float*)d_in[18];

    const int N = in_sizes[0] / 128;
    const int E = in_sizes[3];
    const int NB = (N + 511) / 512;
    const int NB256 = (N + 255) / 256;

    unsigned short* Qb  = (unsigned short*)d_ws;           // N*128 bf16
    unsigned short* KRb = Qb + (size_t)N * 128;            // N*512 bf16
    unsigned short* VMb = KRb + (size_t)N * 512;           // N*512 bf16
    unsigned short* Wqt = VMb + (size_t)N * 512;           // 65536
    unsigned short* Wat = Wqt + 65536;                     // 65536
    unsigned short* Wkrt = Wat + 65536;                    // 262144
    unsigned short* Wvmt = Wkrt + 262144;                  // 262144
    float* bkr = (float*)(Wvmt + 262144);                  // 2048
    float* bvm = bkr + 2048;                               // 2048
    int* order_p = (int*)(bvm + 2048);                     // N+320
    int* blockcnt = order_p + N + 320;                     // NB256*4
    int* boff     = blockcnt + NB256 * 4;                  // NB256*4
    int* pad_off  = boff + NB256 * 4;                      // 8
    int* deg     = pad_off + 8;                            // N
    int* off     = deg + N;                                // N
    int* bsum    = off + N;                                // NB+8
    int* cursorD = bsum + NB + 8;                          // N
    int* elist   = cursorD + N;                            // E
    float* aggr  = (float*)d_out;                          // aliases output (safe: see node_out)

    hipMemsetAsync(order_p, 0xFF, (size_t)(N + 320) * sizeof(int), stream);
    hipMemsetAsync(deg, 0, (size_t)N * sizeof(int), stream);
    hipMemsetAsync(cursorD, 0, (size_t)N * sizeof(int), stream);

    count_types_k<<<NB256, 256, 0, stream>>>(nt, blockcnt, N);
    scan_blocks_k<<<1, 256, 0, stream>>>(blockcnt, NB256, boff, pad_off);
    scatter_types_k<<<NB256, 256, 0, stream>>>(nt, boff, order_p, N);

    convw_k<<<256, 256, 0, stream>>>(Wq, Wa, Wqt, Wat);
    combine_kr_k<<<1024, 256, 0, stream>>>(Wk, rel_att, rel_pri, Wkrt);
    combine_bkr_k<<<8, 256, 0, stream>>>(bk, rel_att, rel_pri, bkr);
    combine_vm_k<<<1024, 256, 0, stream>>>(Wv, rel_msg, Wvmt);
    combine_bvm_k<<<8, 256, 0, stream>>>(bv, rel_msg, bvm);

    deg_k<<<(E + 255) / 256, 256, 0, stream>>>(ei, deg, E);
    scan1_k<<<NB, 512, 0, stream>>>(deg, off, bsum, N);
    scan2_k<<<1, 64, 0, stream>>>(bsum, NB);
    scan3_k<<<NB, 512, 0, stream>>>(off, bsum, N);
    scatter_edges_k<<<(E + 255) / 256, 256, 0, stream>>>(ei, et, off, cursorD, elist, E);

    int nb64 = (N + 252 + 63) / 64;
    proj_mfma<<<nb64, 256, 0, stream>>>(x, order_p, pad_off, Wqt, bq, Wkrt, bkr, Wvmt, bvm,
                                        Qb, KRb, VMb, N);
    edge_fused<<<(N + 3) / 4, 256, 0, stream>>>(Qb, KRb, VMb, off, elist, aggr, N, E);
    node_out_mfma<<<nb64, 256, 0, stream>>>(aggr, x, order_p, pad_off, Wat, ba, skip,
                                            gamma, beta, (float*)d_out, N);
}

// Round 9
// 392.242 us; speedup vs baseline: 5.4828x; 1.3764x over previous
//
#include <hip/hip_runtime.h>
#include <math.h>

#define D_DIM 128

using bf16x8 = __attribute__((ext_vector_type(8))) short;
using f32x4  = __attribute__((ext_vector_type(4))) float;

__device__ __forceinline__ unsigned short f2bf(float f) {
    unsigned u = __float_as_uint(f);
    u += 0x7fffu + ((u >> 16) & 1u);   // RNE
    return (unsigned short)(u >> 16);
}

// ---------------- type sort: ballot-based stable partition (no global atomics) ----------------
__global__ __launch_bounds__(256)
void count_types_k(const int* __restrict__ nt, int* __restrict__ blockcnt, int N) {
    __shared__ int wcnt[4][4];
    int tid = threadIdx.x;
    int i = blockIdx.x * 256 + tid;
    int w = tid >> 6, l = tid & 63;
    int t = (i < N) ? nt[i] : -1;
    #pragma unroll
    for (int tt = 0; tt < 4; ++tt) {
        unsigned long long m = __ballot(t == tt);
        if (l == 0) wcnt[w][tt] = __popcll(m);
    }
    __syncthreads();
    if (tid < 4) {
        blockcnt[blockIdx.x * 4 + tid] =
            wcnt[0][tid] + wcnt[1][tid] + wcnt[2][tid] + wcnt[3][tid];
    }
}

__global__ __launch_bounds__(256)
void scan_blocks_k(const int* __restrict__ blockcnt, int nb,
                   int* __restrict__ boff, int* __restrict__ pad_off) {
    __shared__ int tot_s[4];
    __shared__ int po_s[5];
    int tid = threadIdx.x;
    int t = tid >> 6, l = tid & 63;
    int sum = 0;
    for (int base = 0; base < nb; base += 64) {
        int b = base + l;
        sum += (b < nb) ? blockcnt[b * 4 + t] : 0;
    }
    #pragma unroll
    for (int m = 1; m < 64; m <<= 1) sum += __shfl_xor(sum, m);
    if (l == 0) tot_s[t] = sum;
    __syncthreads();
    if (tid == 0) {
        int s = 0;
        for (int tt = 0; tt < 4; ++tt) { po_s[tt] = s; s += ((tot_s[tt] + 63) >> 6) << 6; }
        po_s[4] = s;
        for (int tt = 0; tt < 5; ++tt) pad_off[tt] = po_s[tt];
    }
    __syncthreads();
    int run = po_s[t];
    for (int base = 0; base < nb; base += 64) {
        int b = base + l;
        int v = (b < nb) ? blockcnt[b * 4 + t] : 0;
        int incl = v;
        #pragma unroll
        for (int off = 1; off < 64; off <<= 1) {
            int up = __shfl_up(incl, off);
            if (l >= off) incl += up;
        }
        if (b < nb) boff[b * 4 + t] = run + incl - v;
        run += __shfl(incl, 63);
    }
}

__global__ __launch_bounds__(256)
void scatter_types_k(const int* __restrict__ nt, const int* __restrict__ boff,
                     int* __restrict__ order_p, int N) {
    __shared__ int wbase[4][4];
    int tid = threadIdx.x;
    int i = blockIdx.x * 256 + tid;
    int w = tid >> 6, l = tid & 63;
    int t = (i < N) ? nt[i] : -1;
    int rank = 0;
    #pragma unroll
    for (int tt = 0; tt < 4; ++tt) {
        unsigned long long m = __ballot(t == tt);
        if (l == 0) wbase[w][tt] = __popcll(m);
        if (t == tt) rank = __popcll(m & ((1ull << l) - 1ull));
    }
    __syncthreads();
    if (tid < 4) {
        int run = 0;
        for (int ww = 0; ww < 4; ++ww) { int c = wbase[ww][tid]; wbase[ww][tid] = run; run += c; }
    }
    __syncthreads();
    if (i < N) order_p[boff[blockIdx.x * 4 + t] + wbase[w][t] + rank] = i;
}

// ---------------- weight convert + transpose to bf16: Wt[t][o][i] ----------------
__global__ void convw_k(const float* __restrict__ Wq, const float* __restrict__ Wa,
                        unsigned short* __restrict__ Wqt, unsigned short* __restrict__ Wat) {
    int i = blockIdx.x * 256 + threadIdx.x;   // 65536 total
    int t = i >> 14, rem = i & 16383, row = rem >> 7, col = rem & 127;
    int d = (t << 14) | (col << 7) | row;
    Wqt[d] = f2bf(Wq[i]);
    Wat[d] = f2bf(Wa[i]);
}

// ---------------- combined Wk·rel_att (pri-scaled): W_kr_t[(t*4+r)][col][i] bf16 ----------------
__global__ void combine_kr_k(const float* __restrict__ Wk, const float* __restrict__ rel_att,
                             const float* __restrict__ rel_pri,
                             unsigned short* __restrict__ W_kr_t) {
    int idx = blockIdx.x * 256 + threadIdx.x;  // 262144 = 16*128*128
    int i = idx & 127;
    int col = (idx >> 7) & 127;
    int r = (idx >> 14) & 3;
    int t = idx >> 16;
    int h = col >> 4, k = col & 15;
    const float* wk = Wk + t * 16384 + i * 128 + h * 16;
    const float* ra = rel_att + ((r * 8 + h) * 16) * 16 + k;
    float s = 0.f;
    #pragma unroll
    for (int d = 0; d < 16; ++d) s += wk[d] * ra[d * 16];
    W_kr_t[idx] = f2bf(s * rel_pri[r * 8 + h] * 0.25f);
}
__global__ void combine_bkr_k(const float* __restrict__ bk, const float* __restrict__ rel_att,
                              const float* __restrict__ rel_pri, float* __restrict__ bkr) {
    int idx = blockIdx.x * 256 + threadIdx.x;  // 2048
    if (idx >= 2048) return;
    int col = idx & 127;
    int r = (idx >> 7) & 3;
    int t = idx >> 9;
    int h = col >> 4, k = col & 15;
    float s = 0.f;
    #pragma unroll
    for (int d = 0; d < 16; ++d)
        s += bk[t * 128 + h * 16 + d] * rel_att[((r * 8 + h) * 16 + d) * 16 + k];
    bkr[idx] = s * rel_pri[r * 8 + h] * 0.25f;
}

// ---------------- combined Wv·rel_msg weights: W_vm_t[(t*4+r)][col][i] bf16 ----------------
__global__ void combine_vm_k(const float* __restrict__ Wv, const float* __restrict__ rel_msg,
                             unsigned short* __restrict__ W_vm_t) {
    int idx = blockIdx.x * 256 + threadIdx.x;  // 262144
    int i = idx & 127;
    int col = (idx >> 7) & 127;
    int r = (idx >> 14) & 3;
    int t = idx >> 16;
    int h = col >> 4, k = col & 15;
    const float* wv = Wv + t * 16384 + i * 128 + h * 16;
    const float* rm = rel_msg + ((r * 8 + h) * 16) * 16 + k;
    float s = 0.f;
    #pragma unroll
    for (int d = 0; d < 16; ++d) s += wv[d] * rm[d * 16];
    W_vm_t[idx] = f2bf(s);
}
__global__ void combine_bvm_k(const float* __restrict__ bv, const float* __restrict__ rel_msg,
                              float* __restrict__ bvm) {
    int idx = blockIdx.x * 256 + threadIdx.x;  // 2048
    if (idx >= 2048) return;
    int col = idx & 127;
    int r = (idx >> 7) & 3;
    int t = idx >> 9;
    int h = col >> 4, k = col & 15;
    float s = 0.f;
    #pragma unroll
    for (int d = 0; d < 16; ++d)
        s += bv[t * 128 + h * 16 + d] * rel_msg[((r * 8 + h) * 16 + d) * 16 + k];
    bvm[idx] = s;
}

// ---------------- dst-CSR build ----------------
__global__ void deg_k(const int* __restrict__ ei, int* __restrict__ deg, int E) {
    int e = blockIdx.x * 256 + threadIdx.x;
    if (e < E) atomicAdd(&deg[ei[E + e]], 1);
}
__global__ void scan1_k(const int* __restrict__ deg, int* __restrict__ excl,
                        int* __restrict__ bsum, int N) {
    __shared__ int s[512];
    int i = blockIdx.x * 512 + threadIdx.x;
    int v = (i < N) ? deg[i] : 0;
    s[threadIdx.x] = v;
    __syncthreads();
    for (int off = 1; off < 512; off <<= 1) {
        int t = (threadIdx.x >= off) ? s[threadIdx.x - off] : 0;
        __syncthreads();
        s[threadIdx.x] += t;
        __syncthreads();
    }
    if (i < N) excl[i] = s[threadIdx.x] - v;
    if (threadIdx.x == 511) bsum[blockIdx.x] = s[511];
}
__global__ void scan2_k(int* __restrict__ bsum, int nb) {
    int l = threadIdx.x & 63;
    int run = 0;
    for (int base = 0; base < nb; base += 64) {
        int b = base + l;
        int v = (b < nb) ? bsum[b] : 0;
        int incl = v;
        #pragma unroll
        for (int off = 1; off < 64; off <<= 1) {
            int up = __shfl_up(incl, off);
            if (l >= off) incl += up;
        }
        if (b < nb) bsum[b] = run + incl - v;
        run += __shfl(incl, 63);
    }
}
__global__ void scan3_k(int* __restrict__ excl, const int* __restrict__ bsum, int N) {
    int i = blockIdx.x * 512 + threadIdx.x;
    if (i < N) excl[i] += bsum[blockIdx.x];
}
__global__ void scatter_edges_k(const int* __restrict__ ei, const int* __restrict__ et,
                                const int* __restrict__ off, int* __restrict__ cursor,
                                int* __restrict__ elist, int E) {
    int e = blockIdx.x * 256 + threadIdx.x;
    if (e < E) {
        int dst = ei[E + e];
        int p = off[dst] + atomicAdd(&cursor[dst], 1);
        elist[p] = (ei[e] << 2) | et[e];
    }
}

// ---------------- MFMA projection (weight-shared): Q + 4 KR + 4 VM rows per node ----------------
// Each wave preloads x fragments for ALL 64 nodes; (matrix,c) weight columns split across waves.
__global__ __launch_bounds__(256, 4)
void proj_mfma(const float* __restrict__ x, const int* __restrict__ order_p,
               const int* __restrict__ pad_off,
               const unsigned short* __restrict__ Wqt, const float* __restrict__ bq,
               const unsigned short* __restrict__ W_kr_t, const float* __restrict__ bkr,
               const unsigned short* __restrict__ W_vm_t, const float* __restrict__ bvm,
               unsigned short* __restrict__ Qb, unsigned short* __restrict__ KRb,
               unsigned short* __restrict__ VMb, int N) {
    __shared__ unsigned shmem[64 * 128];  // 32 KB: first 16 KB = x staging, then reused as output stage
    __shared__ int gid_s[64];
    unsigned* xs = shmem;
    char* stageb = (char*)shmem;
    int tid = threadIdx.x;
    int base = blockIdx.x * 64;
    int t = (base >= pad_off[1]) + (base >= pad_off[2]) + (base >= pad_off[3]);

    if (tid < 64) gid_s[tid] = order_p[base + tid];
    __syncthreads();

    {   // stage x -> bf16 swizzled LDS
        int row = tid >> 2, q = tid & 3;
        int g = gid_s[row];
        const float4* xr = (const float4*)(x + (size_t)(g < 0 ? 0 : g) * 128 + q * 32);
        int swz = (row & 7) << 4;
        #pragma unroll
        for (int v4 = 0; v4 < 8; ++v4) {
            float4 f = (g >= 0) ? xr[v4] : make_float4(0.f, 0.f, 0.f, 0.f);
            unsigned ua = (unsigned)f2bf(f.x) | ((unsigned)f2bf(f.y) << 16);
            unsigned ub = (unsigned)f2bf(f.z) | ((unsigned)f2bf(f.w) << 16);
            int c2 = (q * 16 + v4 * 2) * 4;
            xs[(row << 6) + (((c2) ^ swz) >> 2)] = ua;
            xs[(row << 6) + (((c2 + 4) ^ swz) >> 2)] = ub;
        }
    }
    __syncthreads();

    int w = tid >> 6, l = tid & 63;
    int lr = l & 15, lg = l >> 4;

    // preload x fragments for all 4 node-groups (j*16+lr), all 4 k-slices
    bf16x8 afr[4][4];
    #pragma unroll
    for (int j = 0; j < 4; ++j) {
        int row = j * 16 + lr;
        #pragma unroll
        for (int ks = 0; ks < 4; ++ks) {
            int byteoff = (ks * 64 + lg * 16) ^ ((lr & 7) << 4);
            afr[j][ks] = *reinterpret_cast<const bf16x8*>(
                reinterpret_cast<const char*>(&xs[row << 6]) + byteoff);
        }
    }
    __syncthreads();   // all xs reads done before stage writes overlay it

    // ---- 4 passes: KR mats (0,1),(2,3); VM mats (0,1),(2,3). Wave w owns c = 2w, 2w+1 ----
    #pragma unroll 1
    for (int pass = 0; pass < 4; ++pass) {
        int m0 = (pass & 1) * 2;
        const unsigned short* Wp;
        const float* bp;
        unsigned short* dstp;
        if (pass < 2) { Wp = W_kr_t; bp = bkr; dstp = KRb; }
        else          { Wp = W_vm_t; bp = bvm; dstp = VMb; }
        Wp += (size_t)(t * 4 + m0) << 14;
        bp += (t * 4 + m0) * 128;

        #pragma unroll
        for (int ci = 0; ci < 2; ++ci) {
            int c = w * 2 + ci;
            #pragma unroll
            for (int mm = 0; mm < 2; ++mm) {
                const unsigned short* wb = Wp + ((size_t)mm << 14)
                                         + (size_t)(c * 16 + lr) * 128 + lg * 8;
                bf16x8 wfr[4];
                #pragma unroll
                for (int ks = 0; ks < 4; ++ks) wfr[ks] = *(const bf16x8*)(wb + ks * 32);
                f32x4 acc0 = {0.f,0.f,0.f,0.f}, acc1 = {0.f,0.f,0.f,0.f};
                f32x4 acc2 = {0.f,0.f,0.f,0.f}, acc3 = {0.f,0.f,0.f,0.f};
                #pragma unroll
                for (int ks = 0; ks < 4; ++ks) {
                    acc0 = __builtin_amdgcn_mfma_f32_16x16x32_bf16(wfr[ks], afr[0][ks], acc0, 0, 0, 0);
                    acc1 = __builtin_amdgcn_mfma_f32_16x16x32_bf16(wfr[ks], afr[1][ks], acc1, 0, 0, 0);
                    acc2 = __builtin_amdgcn_mfma_f32_16x16x32_bf16(wfr[ks], afr[2][ks], acc2, 0, 0, 0);
                    acc3 = __builtin_amdgcn_mfma_f32_16x16x32_bf16(wfr[ks], afr[3][ks], acc3, 0, 0, 0);
                }
                float4 bb = *(const float4*)&bp[mm * 128 + c * 16 + lg * 4];
                int colb = (mm * 128 + c * 16 + lg * 4) * 2;
                f32x4 accs[4] = {acc0, acc1, acc2, acc3};
                #pragma unroll
                for (int j = 0; j < 4; ++j) {
                    int node = j * 16 + lr;
                    unsigned p0 = (unsigned)f2bf(accs[j][0] + bb.x) | ((unsigned)f2bf(accs[j][1] + bb.y) << 16);
                    unsigned p1 = (unsigned)f2bf(accs[j][2] + bb.z) | ((unsigned)f2bf(accs[j][3] + bb.w) << 16);
                    int byte = (node * 512 + colb) ^ ((node & 7) << 4);
                    *(uint2*)(stageb + byte) = make_uint2(p0, p1);
                }
            }
        }
        __syncthreads();
        // coalesced drain: wave w drains rows w*16..w*16+15, 2 rows (512 B each) per instr
        #pragma unroll
        for (int i = 0; i < 8; ++i) {
            int row = w * 16 + i * 2 + (l >> 5);
            int l32 = l & 31;
            int byte = (row * 512 + l32 * 16) ^ ((row & 7) << 4);
            uint4 v = *(const uint4*)(stageb + byte);
            int g = gid_s[row];
            if (g >= 0)
                *(uint4*)&dstp[(size_t)g * 512 + (pass & 1) * 256 + l32 * 8] = v;
        }
        __syncthreads();
    }

    // ---- Q pass: wave w owns c = 2w, 2w+1 ----
    #pragma unroll
    for (int ci = 0; ci < 2; ++ci) {
        int c = w * 2 + ci;
        const unsigned short* wb = Wqt + ((size_t)t << 14) + (size_t)(c * 16 + lr) * 128 + lg * 8;
        bf16x8 wfr[4];
        #pragma unroll
        for (int ks = 0; ks < 4; ++ks) wfr[ks] = *(const bf16x8*)(wb + ks * 32);
        f32x4 acc0 = {0.f,0.f,0.f,0.f}, acc1 = {0.f,0.f,0.f,0.f};
        f32x4 acc2 = {0.f,0.f,0.f,0.f}, acc3 = {0.f,0.f,0.f,0.f};
        #pragma unroll
        for (int ks = 0; ks < 4; ++ks) {
            acc0 = __builtin_amdgcn_mfma_f32_16x16x32_bf16(wfr[ks], afr[0][ks], acc0, 0, 0, 0);
            acc1 = __builtin_amdgcn_mfma_f32_16x16x32_bf16(wfr[ks], afr[1][ks], acc1, 0, 0, 0);
            acc2 = __builtin_amdgcn_mfma_f32_16x16x32_bf16(wfr[ks], afr[2][ks], acc2, 0, 0, 0);
            acc3 = __builtin_amdgcn_mfma_f32_16x16x32_bf16(wfr[ks], afr[3][ks], acc3, 0, 0, 0);
        }
        float4 bb = *(const float4*)&bq[t * 128 + c * 16 + lg * 4];
        int colb = (c * 16 + lg * 4) * 2;
        f32x4 accs[4] = {acc0, acc1, acc2, acc3};
        #pragma unroll
        for (int j = 0; j < 4; ++j) {
            int node = j * 16 + lr;
            unsigned p0 = (unsigned)f2bf(accs[j][0] + bb.x) | ((unsigned)f2bf(accs[j][1] + bb.y) << 16);
            unsigned p1 = (unsigned)f2bf(accs[j][2] + bb.z) | ((unsigned)f2bf(accs[j][3] + bb.w) << 16);
            int byte = (node * 256 + colb) ^ ((node & 7) << 4);
            *(uint2*)(stageb + byte) = make_uint2(p0, p1);
        }
    }
    __syncthreads();
    #pragma unroll
    for (int i = 0; i < 4; ++i) {
        int row = w * 16 + i * 4 + (l >> 4);
        int l16 = l & 15;
        int byte = (row * 256 + l16 * 16) ^ ((row & 7) << 4);
        uint4 v = *(const uint4*)(stageb + byte);
        int g = gid_s[row];
        if (g >= 0) *(uint4*)&Qb[(size_t)g * 128 + l16 * 8] = v;
    }
}

// ---------------- fused per-dst edge kernel: one wave per dst, 4 edges per round-trip ----------------
__global__ __launch_bounds__(256)
void edge_fused(const unsigned short* __restrict__ Qb,
                const unsigned short* __restrict__ KRb,
                const unsigned short* __restrict__ VMb,
                const int* __restrict__ off, const int* __restrict__ elist,
                float* __restrict__ aggr, int N, int E) {
    int w = threadIdx.x >> 6, l = threadIdx.x & 63;
    int dst = blockIdx.x * 4 + w;
    if (dst >= N) return;
    int q = l >> 4, c = l & 15;

    float Qf[8];
    {
        bf16x8 qv = *(const bf16x8*)&Qb[(size_t)dst * 128 + c * 8];
        const unsigned* qu = (const unsigned*)&qv;
        #pragma unroll
        for (int i = 0; i < 4; ++i) {
            Qf[2 * i]     = __uint_as_float(qu[i] << 16);
            Qf[2 * i + 1] = __uint_as_float(qu[i] & 0xffff0000u);
        }
    }

    float S[8] = {0.f, 0.f, 0.f, 0.f, 0.f, 0.f, 0.f, 0.f};
    float den = 0.f;

    int e0 = off[dst];
    int e1 = (dst == N - 1) ? E : off[dst + 1];
    int deg = e1 - e0;

    for (int base = 0; base < deg; base += 64) {
        int cnt = min(64, deg - base);
        int pk_l = elist[e0 + min(base + l, deg - 1)];
        for (int s = 0; s < cnt; s += 8) {
            int eA = min(s + q, cnt - 1);
            int eB = min(s + 4 + q, cnt - 1);
            int pkA = __shfl(pk_l, eA);
            int pkB = __shfl(pk_l, eB);
            bf16x8 krA = *(const bf16x8*)&KRb[(size_t)pkA * 128 + c * 8];
            bf16x8 krB = *(const bf16x8*)&KRb[(size_t)pkB * 128 + c * 8];
            bf16x8 vmA = *(const bf16x8*)&VMb[(size_t)pkA * 128 + c * 8];
            bf16x8 vmB = *(const bf16x8*)&VMb[(size_t)pkB * 128 + c * 8];

            const unsigned* ka = (const unsigned*)&krA;
            const unsigned* kb = (const unsigned*)&krB;
            float dtA = 0.f, dtB = 0.f;
            #pragma unroll
            for (int i = 0; i < 4; ++i) {
                dtA = fmaf(Qf[2*i],   __uint_as_float(ka[i] << 16), dtA);
                dtA = fmaf(Qf[2*i+1], __uint_as_float(ka[i] & 0xffff0000u), dtA);
                dtB = fmaf(Qf[2*i],   __uint_as_float(kb[i] << 16), dtB);
                dtB = fmaf(Qf[2*i+1], __uint_as_float(kb[i] & 0xffff0000u), dtB);
            }
            dtA += __shfl_xor(dtA, 1);
            dtB += __shfl_xor(dtB, 1);
            float wA = (s + q < cnt) ? __expf(dtA) : 0.f;
            float wB = (s + 4 + q < cnt) ? __expf(dtB) : 0.f;
            den += wA + wB;

            const unsigned* va = (const unsigned*)&vmA;
            const unsigned* vb = (const unsigned*)&vmB;
            #pragma unroll
            for (int i = 0; i < 4; ++i) {
                S[2*i]   = fmaf(wA, __uint_as_float(va[i] << 16), S[2*i]);
                S[2*i+1] = fmaf(wA, __uint_as_float(va[i] & 0xffff0000u), S[2*i+1]);
                S[2*i]   = fmaf(wB, __uint_as_float(vb[i] << 16), S[2*i]);
                S[2*i+1] = fmaf(wB, __uint_as_float(vb[i] & 0xffff0000u), S[2*i+1]);
            }
        }
    }

    #pragma unroll
    for (int m = 16; m <= 32; m <<= 1) {
        den += __shfl_xor(den, m);
        #pragma unroll
        for (int i = 0; i < 8; ++i) S[i] += __shfl_xor(S[i], m);
    }
    if (q == 0) {
        float inv = (den > 0.f) ? 1.f / den : 0.f;
        float4 o0 = make_float4(S[0]*inv, S[1]*inv, S[2]*inv, S[3]*inv);
        float4 o1 = make_float4(S[4]*inv, S[5]*inv, S[6]*inv, S[7]*inv);
        *(float4*)&aggr[(size_t)dst * 128 + c * 8]     = o0;
        *(float4*)&aggr[(size_t)dst * 128 + c * 8 + 4] = o1;
    }
}

// ---------------- MFMA gelu + Wa proj + skip + LayerNorm (transposed D, aggr aliases d_out) ----------------
__global__ __launch_bounds__(256)
void node_out_mfma(const float* __restrict__ aggr, const float* __restrict__ x,
                   const int* __restrict__ order_p, const int* __restrict__ pad_off,
                   const unsigned short* __restrict__ Wat, const float* __restrict__ ba,
                   const float* __restrict__ skip, const float* __restrict__ gamma,
                   const float* __restrict__ beta, float* __restrict__ out, int N) {
    __shared__ unsigned hsm[64 * 64];
    __shared__ int gid_s[64];
    int tid = threadIdx.x;
    int base = blockIdx.x * 64;
    int t = (base >= pad_off[1]) + (base >= pad_off[2]) + (base >= pad_off[3]);

    if (tid < 64) gid_s[tid] = order_p[base + tid];
    __syncthreads();

    {   // stage gelu(aggr) -> bf16 swizzled LDS (all reads of d_out complete before writes)
        int row = tid >> 2, q = tid & 3;
        int g = gid_s[row];
        const float4* ar = (const float4*)(aggr + (size_t)(g < 0 ? 0 : g) * 128 + q * 32);
        int swz = (row & 7) << 4;
        #pragma unroll
        for (int v4 = 0; v4 < 8; ++v4) {
            float4 f = (g >= 0) ? ar[v4] : make_float4(0.f, 0.f, 0.f, 0.f);
            float g0 = 0.5f * f.x * (1.f + erff(f.x * 0.70710678118654752f));
            float g1 = 0.5f * f.y * (1.f + erff(f.y * 0.70710678118654752f));
            float g2 = 0.5f * f.z * (1.f + erff(f.z * 0.70710678118654752f));
            float g3 = 0.5f * f.w * (1.f + erff(f.w * 0.70710678118654752f));
            unsigned ua = (unsigned)f2bf(g0) | ((unsigned)f2bf(g1) << 16);
            unsigned ub = (unsigned)f2bf(g2) | ((unsigned)f2bf(g3) << 16);
            int c2 = (q * 16 + v4 * 2) * 4;
            hsm[(row << 6) + (((c2) ^ swz) >> 2)] = ua;
            hsm[(row << 6) + (((c2 + 4) ^ swz) >> 2)] = ub;
        }
    }
    __syncthreads();

    int w = tid >> 6, l = tid & 63;
    int rowbase = w * 16, lr = l & 15, lg = l >> 4;
    int myrow = rowbase + lr;

    bf16x8 afr[4];
    #pragma unroll
    for (int ks = 0; ks < 4; ++ks) {
        int byteoff = (ks * 64 + lg * 16) ^ ((lr & 7) << 4);
        afr[ks] = *reinterpret_cast<const bf16x8*>(
            reinterpret_cast<const char*>(&hsm[myrow << 6]) + byteoff);
    }

    float al = 1.f / (1.f + __expf(-skip[t]));
    int g = gid_s[myrow];

    float pre[8][4];
    float s = 0.f, sq = 0.f;

    #pragma unroll
    for (int c = 0; c < 8; ++c) {
        const unsigned short* wb = Wat + ((size_t)t << 14) + (size_t)(c * 16 + lr) * 128 + lg * 8;
        f32x4 acc = {0.f, 0.f, 0.f, 0.f};
        #pragma unroll
        for (int ks = 0; ks < 4; ++ks)
            acc = __builtin_amdgcn_mfma_f32_16x16x32_bf16(
                *(const bf16x8*)(wb + ks * 32), afr[ks], acc, 0, 0, 0);
        float4 bav = *(const float4*)&ba[t * 128 + c * 16 + lg * 4];
        float4 xv = (g >= 0) ? *(const float4*)&x[(size_t)g * 128 + c * 16 + lg * 4]
                             : make_float4(0.f, 0.f, 0.f, 0.f);
        float p0 = (acc[0] + bav.x) * al + xv.x * (1.f - al);
        float p1 = (acc[1] + bav.y) * al + xv.y * (1.f - al);
        float p2 = (acc[2] + bav.z) * al + xv.z * (1.f - al);
        float p3 = (acc[3] + bav.w) * al + xv.w * (1.f - al);
        pre[c][0] = p0; pre[c][1] = p1; pre[c][2] = p2; pre[c][3] = p3;
        s += p0 + p1 + p2 + p3;
        sq += p0 * p0 + p1 * p1 + p2 * p2 + p3 * p3;
    }

    s  += __shfl_xor(s, 16);  sq += __shfl_xor(sq, 16);
    s  += __shfl_xor(s, 32);  sq += __shfl_xor(sq, 32);
    float mu = s * (1.f / 128.f);
    float var = sq * (1.f / 128.f) - mu * mu;
    float rs = rsqrtf(fmaxf(var, 0.f) + 1e-5f);

    #pragma unroll
    for (int c = 0; c < 8; ++c) {
        float4 ga = *(const float4*)&gamma[t * 128 + c * 16 + lg * 4];
        float4 be = *(const float4*)&beta[t * 128 + c * 16 + lg * 4];
        float4 o;
        o.x = (pre[c][0] - mu) * rs * ga.x + be.x;
        o.y = (pre[c][1] - mu) * rs * ga.y + be.y;
        o.z = (pre[c][2] - mu) * rs * ga.z + be.z;
        o.w = (pre[c][3] - mu) * rs * ga.w + be.w;
        if (g >= 0) *(float4*)&out[(size_t)g * 128 + c * 16 + lg * 4] = o;
    }
}

extern "C" void kernel_launch(void* const* d_in, const int* in_sizes, int n_in,
                              void* d_out, int out_size, void* d_ws, size_t ws_size,
                              hipStream_t stream) {
    const float* x   = (const float*)d_in[0];
    const int*   nt  = (const int*)d_in[1];
    const int*   ei  = (const int*)d_in[2];
    const int*   et  = (const int*)d_in[3];
    const float* Wk = (const float*)d_in[5];  const float* bk = (const float*)d_in[6];
    const float* Wq = (const float*)d_in[7];  const float* bq = (const float*)d_in[8];
    const float* Wv = (const float*)d_in[9];  const float* bv = (const float*)d_in[10];
    const float* Wa = (const float*)d_in[11]; const float* ba = (const float*)d_in[12];
    const float* rel_pri = (const float*)d_in[13];
    const float* rel_att = (const float*)d_in[14];
    const float* rel_msg = (const float*)d_in[15];
    const float* skip    = (const float*)d_in[16];
    const float* gamma   = (const float*)d_in[17];
    const float* beta    = (const float*)d_in[18];

    const int N = in_sizes[0] / 128;
    const int E = in_sizes[3];
    const int NB = (N + 511) / 512;
    const int NB256 = (N + 255) / 256;

    unsigned short* Qb  = (unsigned short*)d_ws;           // N*128 bf16
    unsigned short* KRb = Qb + (size_t)N * 128;            // N*512 bf16
    unsigned short* VMb = KRb + (size_t)N * 512;           // N*512 bf16
    unsigned short* Wqt = VMb + (size_t)N * 512;           // 65536
    unsigned short* Wat = Wqt + 65536;                     // 65536
    unsigned short* Wkrt = Wat + 65536;                    // 262144
    unsigned short* Wvmt = Wkrt + 262144;                  // 262144
    float* bkr = (float*)(Wvmt + 262144);                  // 2048
    float* bvm = bkr + 2048;                               // 2048
    int* order_p = (int*)(bvm + 2048);                     // N+320
    int* blockcnt = order_p + N + 320;                     // NB256*4
    int* boff     = blockcnt + NB256 * 4;                  // NB256*4
    int* pad_off  = boff + NB256 * 4;                      // 8
    int* deg     = pad_off + 8;                            // N
    int* off     = deg + N;                                // N
    int* bsum    = off + N;                                // NB+8
    int* cursorD = bsum + NB + 8;                          // N
    int* elist   = cursorD + N;                            // E
    float* aggr  = (float*)d_out;                          // aliases output (safe: see node_out)

    hipMemsetAsync(order_p, 0xFF, (size_t)(N + 320) * sizeof(int), stream);
    hipMemsetAsync(deg, 0, (size_t)N * sizeof(int), stream);
    hipMemsetAsync(cursorD, 0, (size_t)N * sizeof(int), stream);

    count_types_k<<<NB256, 256, 0, stream>>>(nt, blockcnt, N);
    scan_blocks_k<<<1, 256, 0, stream>>>(blockcnt, NB256, boff, pad_off);
    scatter_types_k<<<NB256, 256, 0, stream>>>(nt, boff, order_p, N);

    convw_k<<<256, 256, 0, stream>>>(Wq, Wa, Wqt, Wat);
    combine_kr_k<<<1024, 256, 0, stream>>>(Wk, rel_att, rel_pri, Wkrt);
    combine_bkr_k<<<8, 256, 0, stream>>>(bk, rel_att, rel_pri, bkr);
    combine_vm_k<<<1024, 256, 0, stream>>>(Wv, rel_msg, Wvmt);
    combine_bvm_k<<<8, 256, 0, stream>>>(bv, rel_msg, bvm);

    deg_k<<<(E + 255) / 256, 256, 0, stream>>>(ei, deg, E);
    scan1_k<<<NB, 512, 0, stream>>>(deg, off, bsum, N);
    scan2_k<<<1, 64, 0, stream>>>(bsum, NB);
    scan3_k<<<NB, 512, 0, stream>>>(off, bsum, N);
    scatter_edges_k<<<(E + 255) / 256, 256, 0, stream>>>(ei, et, off, cursorD, elist, E);

    int nb64 = (N + 252 + 63) / 64;
    proj_mfma<<<nb64, 256, 0, stream>>>(x, order_p, pad_off, Wqt, bq, Wkrt, bkr, Wvmt, bvm,
                                        Qb, KRb, VMb, N);
    edge_fused<<<(N + 3) / 4, 256, 0, stream>>>(Qb, KRb, VMb, off, elist, aggr, N, E);
    node_out_mfma<<<nb64, 256, 0, stream>>>(aggr, x, order_p, pad_off, Wat, ba, skip,
                                            gamma, beta, (float*)d_out, N);
}